// Round 19
// baseline (2050.529 us; speedup 1.0000x reference)
//
#include <hip/hip_runtime.h>
#include <hip/hip_bf16.h>
#include <math.h>

#define B_ 4
#define T_ 1024
#define D_ 1024
#define H_ 16
#define DH_ 64
#define M_ 4096
#define QSTR_ 3072   // fused qkv row stride
#define EPS_ 1e-5f

typedef __attribute__((ext_vector_type(4))) float f32x4;
typedef __attribute__((ext_vector_type(8))) short s16x8;

#if __has_builtin(__builtin_amdgcn_exp2f)
#define EXP2F __builtin_amdgcn_exp2f
#else
#define EXP2F exp2f
#endif

__device__ __forceinline__ float gelu_f(float x) {
  return 0.5f * x * (1.0f + erff(x * 0.70710678118654752f));
}
__device__ __forceinline__ float b2f(unsigned short u) {
  union { unsigned int i; float f; } c; c.i = ((unsigned int)u) << 16; return c.f;
}
__device__ __forceinline__ unsigned short f2b(float f) {
  __hip_bfloat16 h = __float2bfloat16(f);
  return *reinterpret_cast<unsigned short*>(&h);
}
__device__ __forceinline__ void g2l16(void* l, const void* g) {
  __builtin_amdgcn_global_load_lds(
      (const __attribute__((address_space(1))) void*)g,
      (__attribute__((address_space(3))) void*)l, 16, 0, 0);
}

struct TrAll {
  const float *wq, *wk, *wv, *wp, *w1, *w2;
  __hip_bfloat16 *dqkv, *dp, *d1, *d2;
};

// ---------------- LayerNorm body (one 256-thr block per row) ----------------
template<bool BF16OUT, bool ADDP>
__device__ __forceinline__ void ln_body(
    int row, float* __restrict__ xio, const float* __restrict__ part,
    void* __restrict__ out,
    const float* __restrict__ g, const float* __restrict__ b) {
  const int tid = threadIdx.x;
  float* rp = xio + (size_t)row * D_;
  float4 v = *reinterpret_cast<const float4*>(rp + tid * 4);
  if (ADDP) {
    float4 pv = *reinterpret_cast<const float4*>(part + (size_t)row * D_ + tid * 4);
    v.x += pv.x; v.y += pv.y; v.z += pv.z; v.w += pv.w;
    *reinterpret_cast<float4*>(rp + tid * 4) = v;  // write back summed residual
  }
  float s = v.x + v.y + v.z + v.w;
  float s2 = v.x * v.x + v.y * v.y + v.z * v.z + v.w * v.w;
#pragma unroll
  for (int off = 1; off < 64; off <<= 1) {
    s += __shfl_xor(s, off);
    s2 += __shfl_xor(s2, off);
  }
  __shared__ float red[2][4];
  const int wid = tid >> 6;
  if ((tid & 63) == 0) { red[0][wid] = s; red[1][wid] = s2; }
  __syncthreads();
  s = red[0][0] + red[0][1] + red[0][2] + red[0][3];
  s2 = red[1][0] + red[1][1] + red[1][2] + red[1][3];
  const float mu = s * (1.0f / D_);
  const float var = s2 * (1.0f / D_) - mu * mu;
  const float rs = rsqrtf(var + EPS_);
  float4 gv = *reinterpret_cast<const float4*>(g + tid * 4);
  float4 bv = *reinterpret_cast<const float4*>(b + tid * 4);
  float o0 = (v.x - mu) * rs * gv.x + bv.x;
  float o1 = (v.y - mu) * rs * gv.y + bv.y;
  float o2 = (v.z - mu) * rs * gv.z + bv.z;
  float o3 = (v.w - mu) * rs * gv.w + bv.w;
  if (BF16OUT) {
    ushort4 pk;
    pk.x = f2b(o0); pk.y = f2b(o1); pk.z = f2b(o2); pk.w = f2b(o3);
    *reinterpret_cast<ushort4*>((unsigned short*)out + (size_t)row * D_ + tid * 4) = pk;
  } else {
    *reinterpret_cast<float4*>((float*)out + (size_t)row * D_ + tid * 4) =
        make_float4(o0, o1, o2, o3);
  }
}

template<bool BF16OUT, bool ADDP>
__global__ __launch_bounds__(256) void ln_kernel(
    float* __restrict__ xio, const float* __restrict__ part,
    void* __restrict__ out,
    const float* __restrict__ g, const float* __restrict__ b) {
  ln_body<BF16OUT, ADDP>(blockIdx.x, xio, part, out, g, b);
}

// ---------------- transpose tile body ----------------
__device__ __forceinline__ void transpose_tile(
    const float* __restrict__ src, int sld,
    __hip_bfloat16* __restrict__ dst, int dld, int k0, int n0) {
  __shared__ float tile[32][33];
  const int t = threadIdx.x;
  const int r = t >> 3;
  const int cq = (t & 7) * 4;
  float4 vv = *reinterpret_cast<const float4*>(src + (size_t)(k0 + r) * sld + n0 + cq);
  tile[r][cq + 0] = vv.x; tile[r][cq + 1] = vv.y;
  tile[r][cq + 2] = vv.z; tile[r][cq + 3] = vv.w;
  __syncthreads();
  ushort4 o;
  o.x = f2b(tile[cq + 0][r]); o.y = f2b(tile[cq + 1][r]);
  o.z = f2b(tile[cq + 2][r]); o.w = f2b(tile[cq + 3][r]);
  *reinterpret_cast<ushort4*>((unsigned short*)dst + (size_t)(n0 + r) * dld + k0 + cq) = o;
}

__device__ __forceinline__ void transpose_dispatch(int t, const TrAll& a) {
  const float* src;
  __hip_bfloat16* dst;
  int sld, dld, k0, n0;
  if (t < 4096) {
    const int m = t >> 10, tile = t & 1023;
    k0 = (tile >> 5) * 32; n0 = (tile & 31) * 32;
    src = (m == 0) ? a.wq : (m == 1) ? a.wk : (m == 2) ? a.wv : a.wp;
    sld = 1024; dld = 1024;
    dst = (m < 3) ? (a.dqkv + (size_t)m * 1024 * 1024) : a.dp;
  } else if (t < 8192) {
    const int tile = t - 4096;
    k0 = (tile & 31) * 32; n0 = (tile >> 5) * 32;
    src = a.w1; sld = 4096; dst = a.d1; dld = 1024;
  } else {
    const int tile = t - 8192;
    k0 = (tile >> 5) * 32; n0 = (tile & 31) * 32;
    src = a.w2; sld = 1024; dst = a.d2; dld = 4096;
  }
  transpose_tile(src, sld, dst, dld, k0, n0);
}

// ---------------- fused: ln1 (rows 0..4095) + all weight transposes ----------------
template<bool ADDP>
__global__ __launch_bounds__(256) void ln_tr_fused(
    float* __restrict__ xio, const float* __restrict__ part,
    void* __restrict__ out,
    const float* __restrict__ g, const float* __restrict__ b, TrAll a) {
  if (blockIdx.x < M_) {
    ln_body<true, ADDP>(blockIdx.x, xio, part, out, g, b);
  } else {
    transpose_dispatch(blockIdx.x - M_, a);
  }
}

// ---------------- bias concat: [L][3072] <- bq|bk|bv ----------------
__global__ __launch_bounds__(256) void concat_bias(
    const float* __restrict__ bq, const float* __restrict__ bk,
    const float* __restrict__ bv, float* __restrict__ out) {
  const int i = blockIdx.x * 256 + threadIdx.x;
  const int l = i / QSTR_, c = i % QSTR_;
  const float* src = (c < 1024) ? bq : ((c < 2048) ? bk : bv);
  out[i] = src[l * 1024 + (c & 1023)];
}

// ---------------- bf16 MFMA GEMM 128xBN (4 waves): 3-deep pipeline + swizzle ----
// MODE 0: store bf16; MODE 1: fp32 C += result; MODE 2: store bf16 gelu(result)
template<int MODE, int BN>
__global__ __launch_bounds__(256) void gemm_mfma(
    const __hip_bfloat16* __restrict__ A,
    const __hip_bfloat16* __restrict__ Bt,
    const float* __restrict__ bias,
    void* __restrict__ Cout, int N, int K) {
  __shared__ short As[3][128 * 32];
  __shared__ short Bs[3][BN * 32];
  int bid = blockIdx.y * gridDim.x + blockIdx.x;
  const int nwg = gridDim.x * gridDim.y;
  bid = (bid & 7) * (nwg >> 3) + (bid >> 3);
  const int gn = (bid % gridDim.x) * BN;
  const int gm = (bid / gridDim.x) * 128;

  const int tid = threadIdx.x;
  const int wid = tid >> 6, lane = tid & 63;
  constexpr int MR = (BN == 128) ? 4 : 2;
  const int wm = (BN == 128) ? (wid >> 1) : wid;
  const int wn = (BN == 128) ? (wid & 1) : 0;
  const int fr = lane & 15, kg = lane >> 4;

  const int ldr = lane >> 2;
  const int ldk = (((lane & 3) ^ ((lane >> 3) & 3)) * 8);  // pre-swizzled source chunk
  const unsigned short* ap =
      (const unsigned short*)A + (size_t)(gm + wid * 32 + ldr) * K + ldk;
  const unsigned short* bp =
      (const unsigned short*)Bt +
      (size_t)(gn + ((BN == 128) ? wid * 32 : wid * 16) + ldr) * K + ldk;

  const int nkt = K >> 5;

#define STAGE_T(t, buf)                                                    \
  {                                                                        \
    const unsigned short* a_ = ap + (size_t)(t) * 32;                      \
    g2l16((char*)As[buf] + (wid * 2) * 1024, a_);                          \
    g2l16((char*)As[buf] + (wid * 2 + 1) * 1024, a_ + (size_t)16 * K);     \
    const unsigned short* b_ = bp + (size_t)(t) * 32;                      \
    if (BN == 128) {                                                       \
      g2l16((char*)Bs[buf] + (wid * 2) * 1024, b_);                        \
      g2l16((char*)Bs[buf] + (wid * 2 + 1) * 1024, b_ + (size_t)16 * K);   \
    } else {                                                               \
      g2l16((char*)Bs[buf] + wid * 1024, b_);                              \
    }                                                                      \
  }

  STAGE_T(0, 0);
  STAGE_T(1, 1);

  const int cxa = (kg ^ ((fr >> 1) & 3)) * 8;  // swizzled read chunk (shorts)
  f32x4 acc[MR][4] = {};
  for (int t = 0; t < nkt; ++t) {
    const int buf = t % 3;
    if (t + 2 < nkt) STAGE_T(t + 2, (t + 2) % 3);
    const int rem = nkt - 1 - t;
    if (rem >= 2) {
      if (BN == 128) asm volatile("s_waitcnt vmcnt(8)" ::: "memory");
      else           asm volatile("s_waitcnt vmcnt(6)" ::: "memory");
    } else if (rem == 1) {
      if (BN == 128) asm volatile("s_waitcnt vmcnt(4)" ::: "memory");
      else           asm volatile("s_waitcnt vmcnt(3)" ::: "memory");
    } else {
      asm volatile("s_waitcnt vmcnt(0)" ::: "memory");
    }
    __builtin_amdgcn_s_barrier();
    __builtin_amdgcn_sched_barrier(0);
    s16x8 af[MR], bfr[4];
#pragma unroll
    for (int m = 0; m < MR; ++m)
      af[m] = *reinterpret_cast<const s16x8*>(
          &As[buf][(wm * (16 * MR) + m * 16 + fr) * 32 + cxa]);
#pragma unroll
    for (int n = 0; n < 4; ++n)
      bfr[n] = *reinterpret_cast<const s16x8*>(
          &Bs[buf][(wn * 64 + n * 16 + fr) * 32 + cxa]);
#pragma unroll
    for (int m = 0; m < MR; ++m)
#pragma unroll
      for (int n = 0; n < 4; ++n)
        acc[m][n] = __builtin_amdgcn_mfma_f32_16x16x32_bf16(af[m], bfr[n], acc[m][n], 0, 0, 0);
    __builtin_amdgcn_sched_barrier(0);
    __builtin_amdgcn_s_barrier();
  }
#undef STAGE_T

  const int r0 = gm + wm * (16 * MR);
  const int c0 = gn + wn * 64;
  float bb[4];
#pragma unroll
  for (int n = 0; n < 4; ++n)
    bb[n] = bias ? bias[c0 + n * 16 + fr] : 0.0f;
#pragma unroll
  for (int m = 0; m < MR; ++m) {
#pragma unroll
    for (int j = 0; j < 4; ++j) {
      const int row = r0 + m * 16 + kg * 4 + j;
#pragma unroll
      for (int n = 0; n < 4; ++n) {
        float val = acc[m][n][j] + bb[n];
        const size_t idx = (size_t)row * N + c0 + n * 16 + fr;
        if (MODE == 0) {
          ((unsigned short*)Cout)[idx] = f2b(val);
        } else if (MODE == 1) {
          float* cp = (float*)Cout + idx;
          *cp = *cp + val;
        } else {
          ((unsigned short*)Cout)[idx] = f2b(gelu_f(val));
        }
      }
    }
  }
}

// ------- 128x256 wide GEMM (8 waves, 512 thr): halves B-side cache traffic -------
// MODE: 0 store bf16; 1 fp32 +=; 2 gelu bf16; 3 split-K (z0: X+=acc+bias, z1: P=acc)
template<int MODE>
__global__ __launch_bounds__(512) void gemm_w256(
    const __hip_bfloat16* __restrict__ A,
    const __hip_bfloat16* __restrict__ Bt,
    const float* __restrict__ bias,
    void* __restrict__ Cout, float* __restrict__ P,
    int N, int K, int KS) {
  __shared__ short As[3][128 * 32];
  __shared__ short Bs[3][256 * 32];
  int bid = blockIdx.y * gridDim.x + blockIdx.x;
  const int nwg = gridDim.x * gridDim.y;
  bid = (bid & 7) * (nwg >> 3) + (bid >> 3);
  const int gn = (bid % gridDim.x) * 256;
  const int gm = (bid / gridDim.x) * 128;
  const int koff = (MODE == 3) ? blockIdx.z * KS : 0;

  const int tid = threadIdx.x;
  const int wid = tid >> 6, lane = tid & 63;
  const int wm = wid & 1, wn = wid >> 1;  // 2 x 4 waves of 64x64
  const int fr = lane & 15, kg = lane >> 4;

  const int ldr = lane >> 2;
  const int ldk = (((lane & 3) ^ ((lane >> 3) & 3)) * 8);
  const unsigned short* ap =
      (const unsigned short*)A + (size_t)(gm + wid * 16 + ldr) * K + koff + ldk;
  const unsigned short* bp =
      (const unsigned short*)Bt + (size_t)(gn + wid * 32 + ldr) * K + koff + ldk;

  const int nkt = ((MODE == 3) ? KS : K) >> 5;

#define STAGE_W(t, buf)                                                    \
  {                                                                        \
    g2l16((char*)As[buf] + wid * 1024, ap + (size_t)(t) * 32);             \
    const unsigned short* b_ = bp + (size_t)(t) * 32;                      \
    g2l16((char*)Bs[buf] + (wid * 2) * 1024, b_);                          \
    g2l16((char*)Bs[buf] + (wid * 2 + 1) * 1024, b_ + (size_t)16 * K);     \
  }

  STAGE_W(0, 0);
  STAGE_W(1, 1);

  const int cxa = (kg ^ ((fr >> 1) & 3)) * 8;
  f32x4 acc[4][4] = {};
  for (int t = 0; t < nkt; ++t) {
    const int buf = t % 3;
    if (t + 2 < nkt) STAGE_W(t + 2, (t + 2) % 3);
    const int rem = nkt - 1 - t;
    if (rem >= 2)      asm volatile("s_waitcnt vmcnt(6)" ::: "memory");
    else if (rem == 1) asm volatile("s_waitcnt vmcnt(3)" ::: "memory");
    else               asm volatile("s_waitcnt vmcnt(0)" ::: "memory");
    __builtin_amdgcn_s_barrier();
    __builtin_amdgcn_sched_barrier(0);
    s16x8 af[4], bfr[4];
#pragma unroll
    for (int m = 0; m < 4; ++m)
      af[m] = *reinterpret_cast<const s16x8*>(
          &As[buf][(wm * 64 + m * 16 + fr) * 32 + cxa]);
#pragma unroll
    for (int n = 0; n < 4; ++n)
      bfr[n] = *reinterpret_cast<const s16x8*>(
          &Bs[buf][(wn * 64 + n * 16 + fr) * 32 + cxa]);
#pragma unroll
    for (int m = 0; m < 4; ++m)
#pragma unroll
      for (int n = 0; n < 4; ++n)
        acc[m][n] = __builtin_amdgcn_mfma_f32_16x16x32_bf16(af[m], bfr[n], acc[m][n], 0, 0, 0);
    __builtin_amdgcn_sched_barrier(0);
    __builtin_amdgcn_s_barrier();
  }
#undef STAGE_W

  const int r0 = gm + wm * 64;
  const int c0 = gn + wn * 64;
  if (MODE == 3 && blockIdx.z == 1) {
#pragma unroll
    for (int m = 0; m < 4; ++m)
#pragma unroll
      for (int j = 0; j < 4; ++j) {
        const int row = r0 + m * 16 + kg * 4 + j;
#pragma unroll
        for (int n = 0; n < 4; ++n)
          P[(size_t)row * N + c0 + n * 16 + fr] = acc[m][n][j];
      }
    return;
  }
  float bb[4];
#pragma unroll
  for (int n = 0; n < 4; ++n)
    bb[n] = bias ? bias[c0 + n * 16 + fr] : 0.0f;
#pragma unroll
  for (int m = 0; m < 4; ++m) {
#pragma unroll
    for (int j = 0; j < 4; ++j) {
      const int row = r0 + m * 16 + kg * 4 + j;
#pragma unroll
      for (int n = 0; n < 4; ++n) {
        float val = acc[m][n][j] + bb[n];
        const size_t idx = (size_t)row * N + c0 + n * 16 + fr;
        if (MODE == 0) {
          ((unsigned short*)Cout)[idx] = f2b(val);
        } else if (MODE == 1 || MODE == 3) {
          float* cp = (float*)Cout + idx;
          *cp = *cp + val;
        } else {
          ((unsigned short*)Cout)[idx] = f2b(gelu_f(val));
        }
      }
    }
  }
}

// ------- 256x256 phase-scheduled GEMM (8 waves, BK=64, 128KB dynamic LDS) -------
__global__ __launch_bounds__(512) void gemm_8ph(
    const __hip_bfloat16* __restrict__ A,
    const __hip_bfloat16* __restrict__ Bt,
    const float* __restrict__ bias,
    unsigned short* __restrict__ Cout, int N, int K) {
  extern __shared__ short sm8[];  // 2 halves x (A 256x64 + B 256x64) = 128KB
  int bid = blockIdx.y * gridDim.x + blockIdx.x;
  const int nwg = gridDim.x * gridDim.y;
  bid = (bid & 7) * (nwg >> 3) + (bid >> 3);
  const int gn = (bid % gridDim.x) * 256;
  const int gm = (bid / gridDim.x) * 256;
  const int tid = threadIdx.x;
  const int wid = tid >> 6, lane = tid & 63;
  const int wm = wid >> 2, wn = wid & 3;   // 2m x 4n
  const int fr = lane & 15, kg = lane >> 4;
  const int r8 = lane >> 3, cp = lane & 7;
  const unsigned short* Ap = (const unsigned short*)A;
  const unsigned short* Bp = (const unsigned short*)Bt;
  const int nkt = K >> 6;

#define STAGE8(t, hbase, u)                                                  \
  {                                                                          \
    const int row_ = (u) * 64 + wid * 8 + r8;                                \
    const int c16_ = cp ^ (row_ & 7);                                        \
    g2l16((hbase) + ((u) * 64 + wid * 8) * 128,                              \
          Ap + (size_t)(gm + row_) * K + (size_t)(t) * 64 + c16_ * 8);       \
    g2l16((hbase) + 32768 + ((u) * 64 + wid * 8) * 128,                      \
          Bp + (size_t)(gn + row_) * K + (size_t)(t) * 64 + c16_ * 8);       \
  }

#pragma unroll
  for (int u = 0; u < 4; ++u) STAGE8(0, (char*)sm8, u);
  asm volatile("s_waitcnt vmcnt(0)" ::: "memory");
  __builtin_amdgcn_s_barrier();

  f32x4 acc[8][4] = {};
  for (int t = 0; t < nkt; ++t) {
    char* cur = (char*)sm8 + (t & 1) * 65536;
    char* nxt = (char*)sm8 + ((t & 1) ^ 1) * 65536;
    __builtin_amdgcn_sched_barrier(0);
#pragma unroll
    for (int p = 0; p < 4; ++p) {
      if (t + 1 < nkt) STAGE8(t + 1, nxt, p);
      s16x8 af[2][2], bfr[4][2];
#pragma unroll
      for (int mm = 0; mm < 2; ++mm) {
        const int row = wm * 128 + (p * 2 + mm) * 16 + fr;
#pragma unroll
        for (int kk = 0; kk < 2; ++kk)
          af[mm][kk] = *reinterpret_cast<const s16x8*>(
              cur + row * 128 + (((kk * 4 + kg) ^ (row & 7)) << 4));
      }
#pragma unroll
      for (int n = 0; n < 4; ++n) {
        const int row = wn * 64 + n * 16 + fr;
#pragma unroll
        for (int kk = 0; kk < 2; ++kk)
          bfr[n][kk] = *reinterpret_cast<const s16x8*>(
              cur + 32768 + row * 128 + (((kk * 4 + kg) ^ (row & 7)) << 4));
      }
      __builtin_amdgcn_s_setprio(1);
#pragma unroll
      for (int kk = 0; kk < 2; ++kk)
#pragma unroll
        for (int mm = 0; mm < 2; ++mm)
#pragma unroll
          for (int n = 0; n < 4; ++n)
            acc[p * 2 + mm][n] = __builtin_amdgcn_mfma_f32_16x16x32_bf16(
                af[mm][kk], bfr[n][kk], acc[p * 2 + mm][n], 0, 0, 0);
      __builtin_amdgcn_s_setprio(0);
    }
    if (t + 1 < nkt) {
      asm volatile("s_waitcnt vmcnt(0)" ::: "memory");
      __builtin_amdgcn_s_barrier();
    }
  }
#undef STAGE8

  const int r0 = gm + wm * 128;
  const int c0 = gn + wn * 64;
  float bb[4];
#pragma unroll
  for (int n = 0; n < 4; ++n) bb[n] = bias[c0 + n * 16 + fr];
#pragma unroll
  for (int m = 0; m < 8; ++m)
#pragma unroll
    for (int j = 0; j < 4; ++j) {
      const int row = r0 + m * 16 + kg * 4 + j;
#pragma unroll
      for (int n = 0; n < 4; ++n)
        Cout[(size_t)row * N + c0 + n * 16 + fr] =
            f2b(gelu_f(acc[m][n][j] + bb[n]));
    }
}

// ---------------- MFMA flash attention v7: QBLK=256, 8 waves, swapped softmax ----
__global__ __launch_bounds__(512) void attn_mfma(
    const __hip_bfloat16* __restrict__ qkv, __hip_bfloat16* __restrict__ yg) {
  const int x = blockIdx.x;
  const int qb = (x < 2) ? (3 - x) : (x - 2);  // balanced pairing (3,0),(2,1)
  const int hh = blockIdx.y;
  const int bb = blockIdx.z;
  __shared__ short Qs[256 * 64];    // Q staging, then P (32KB)
  __shared__ short Ks[2][64 * 64];  // 16KB
  __shared__ short Vt[64 * 64];     // 8KB, single buffer
  const int tid = threadIdx.x;
  const int wid = tid >> 6, lane = tid & 63;
  const int fr = lane & 15, kg = lane >> 4;
  const size_t qb_base = (size_t)bb * T_ * QSTR_ + (size_t)hh * DH_;
  const unsigned short* qgp = (const unsigned short*)qkv + qb_base;
  const unsigned short* kgp = qgp + 1024;
  const unsigned short* vgp = qgp + 2048;
  const float C = 0.125f * 1.4426950408889634f;  // scale * log2(e)

  const int r8 = lane >> 3, cp = lane & 7;
#pragma unroll
  for (int u = 0; u < 4; ++u) {
    const int row = wid * 32 + u * 8 + r8;
    const int c16 = cp ^ (row & 7);
    g2l16((char*)Qs + (wid * 32 + u * 8) * 128,
          qgp + (size_t)(qb * 256 + row) * QSTR_ + c16 * 8);
  }
  {
    const int row = wid * 8 + r8;
    const int c16 = cp ^ (row & 7);
    g2l16((char*)Ks[0] + (wid * 8) * 128, kgp + (size_t)row * QSTR_ + c16 * 8);
  }
  const int kv0 = tid >> 3;
  const int d0 = (tid & 7) * 8;
  const int rot = tid & 7;
  s16x8 sva = *reinterpret_cast<const s16x8*>(vgp + (size_t)kv0 * QSTR_ + d0);

  asm volatile("s_waitcnt vmcnt(0)" ::: "memory");
  __syncthreads();
  s16x8 qf[2][2];
#pragma unroll
  for (int rg = 0; rg < 2; ++rg) {
    const int row = wid * 32 + rg * 16 + fr;
    const char* rp = (const char*)Qs + row * 128;
    qf[rg][0] = *reinterpret_cast<const s16x8*>(rp + (((0 + kg) ^ (row & 7)) << 4));
    qf[rg][1] = *reinterpret_cast<const s16x8*>(rp + (((4 + kg) ^ (row & 7)) << 4));
  }

  f32x4 acco[2][4] = {};
  float m_run[2] = {-INFINITY, -INFINITY};
  float l_run[2] = {0.f, 0.f};

  const int q16hi = qb * 16 + wid * 2 + 1;
  const int ntile = 4 * qb + 4;
  for (int kt = 0; kt < ntile; ++kt) {
    const int buf = kt & 1;
    if (kt > 0) __syncthreads();
    asm volatile("s_waitcnt vmcnt(0)" ::: "memory");
#pragma unroll
    for (int j = 0; j < 8; ++j) {
      const int jj = (j + rot) & 7;
      const int d = d0 + jj;
      *(short*)((char*)Vt + d * 128 + ((((kv0 >> 3) ^ jj) & 7) << 4) + (kv0 & 7) * 2) = sva[jj];
    }
    if (kt + 1 < ntile) {
      const int row = wid * 8 + r8;
      const int c16 = cp ^ (row & 7);
      g2l16((char*)Ks[buf ^ 1] + (wid * 8) * 128,
            kgp + (size_t)((kt + 1) * 64 + row) * QSTR_ + c16 * 8);
      sva = *reinterpret_cast<const s16x8*>(
          vgp + (size_t)((kt + 1) * 64 + kv0) * QSTR_ + d0);
    }
    __syncthreads();
    __builtin_amdgcn_sched_barrier(0);

    if (kt * 4 <= q16hi) {
      f32x4 accs[2][4] = {};
      __builtin_amdgcn_s_setprio(1);
#pragma unroll
      for (int n = 0; n < 4; ++n) {
        const int row = n * 16 + fr;
        const char* rp = (const char*)Ks[buf] + row * 128;
        s16x8 kf0 = *reinterpret_cast<const s16x8*>(rp + (((0 + kg) ^ (row & 7)) << 4));
        s16x8 kf1 = *reinterpret_cast<const s16x8*>(rp + (((4 + kg) ^ (row & 7)) << 4));
#pragma unroll
        for (int rg = 0; rg < 2; ++rg) {
          accs[rg][n] = __builtin_amdgcn_mfma_f32_16x16x32_bf16(kf0, qf[rg][0], accs[rg][n], 0, 0, 0);
          accs[rg][n] = __builtin_amdgcn_mfma_f32_16x16x32_bf16(kf1, qf[rg][1], accs[rg][n], 0, 0, 0);
        }
      }
      __builtin_amdgcn_s_setprio(0);
      float aj[2][4];
#pragma unroll
      for (int rg = 0; rg < 2; ++rg) {
        const int q16 = qb * 16 + wid * 2 + rg;
        float mloc = -3.0e38f;
#pragma unroll
        for (int n = 0; n < 4; ++n)
          if (kt * 4 + n <= q16)
#pragma unroll
            for (int j = 0; j < 4; ++j) mloc = fmaxf(mloc, accs[rg][n][j]);
        mloc = fmaxf(mloc, __shfl_xor(mloc, 16));
        mloc = fmaxf(mloc, __shfl_xor(mloc, 32));
        const float mn = fmaxf(m_run[rg], mloc);
        const float a_ = EXP2F((m_run[rg] - mn) * C);
        m_run[rg] = mn;
        const int prow = wid * 32 + rg * 16 + fr;
        char* pbase = (char*)Qs + prow * 128 + (kg & 1) * 8;
        const int rxor = prow & 7;
        float psum = 0.f;
#pragma unroll
        for (int n = 0; n < 4; ++n) {
          const bool dead = (kt * 4 + n > q16);
          unsigned long long pk = 0;
#pragma unroll
          for (int j = 0; j < 4; ++j) {
            const float p = dead ? 0.0f : EXP2F((accs[rg][n][j] - mn) * C);
            psum += p;
            pk |= (unsigned long long)f2b(p) << (16 * j);
          }
          *reinterpret_cast<unsigned long long*>(
              pbase + (((n * 2 + (kg >> 1)) ^ rxor) << 4)) = pk;
        }
        l_run[rg] = l_run[rg] * a_ + psum;
#pragma unroll
        for (int j = 0; j < 4; ++j) aj[rg][j] = __shfl(a_, kg * 4 + j);
#pragma unroll
        for (int dt = 0; dt < 4; ++dt)
#pragma unroll
          for (int j = 0; j < 4; ++j) acco[rg][dt][j] *= aj[rg][j];
      }
      __builtin_amdgcn_s_setprio(1);
#pragma unroll
      for (int rg = 0; rg < 2; ++rg) {
        const int prow = wid * 32 + rg * 16 + fr;
        const char* pp = (const char*)Qs + prow * 128;
#pragma unroll
        for (int kk = 0; kk < 2; ++kk) {
          const s16x8 pf = *reinterpret_cast<const s16x8*>(
              pp + ((((kk * 4 + kg) ^ (prow & 7)) & 7) << 4));
#pragma unroll
          for (int dt = 0; dt < 4; ++dt) {
            const int vrow = dt * 16 + fr;
            const s16x8 vf = *reinterpret_cast<const s16x8*>(
                (const char*)Vt + vrow * 128 + ((((kk * 4 + kg) ^ (vrow & 7)) & 7) << 4));
            acco[rg][dt] = __builtin_amdgcn_mfma_f32_16x16x32_bf16(pf, vf, acco[rg][dt], 0, 0, 0);
          }
        }
      }
      __builtin_amdgcn_s_setprio(0);
    }
  }

  unsigned short* yp = (unsigned short*)yg + (size_t)bb * T_ * D_ + (size_t)hh * DH_;
#pragma unroll
  for (int rg = 0; rg < 2; ++rg) {
    float lt = l_run[rg];
    lt += __shfl_xor(lt, 16);
    lt += __shfl_xor(lt, 32);
    const float linv = 1.0f / lt;
    float lj[4];
#pragma unroll
    for (int j = 0; j < 4; ++j) lj[j] = __shfl(linv, kg * 4 + j);
#pragma unroll
    for (int dt = 0; dt < 4; ++dt)
#pragma unroll
      for (int j = 0; j < 4; ++j) {
        const int row = qb * 256 + wid * 32 + rg * 16 + kg * 4 + j;
        yp[(size_t)row * D_ + dt * 16 + fr] = f2b(acco[rg][dt][j] * lj[j]);
      }
  }
}

extern "C" void kernel_launch(void* const* d_in, const int* in_sizes, int n_in,
                              void* d_out, int out_size, void* d_ws, size_t ws_size,
                              hipStream_t stream) {
  (void)in_sizes; (void)n_in; (void)out_size; (void)ws_size;
  const float* seq  = (const float*)d_in[0];
  const float* Wq   = (const float*)d_in[1];
  const float* bq   = (const float*)d_in[2];
  const float* Wk   = (const float*)d_in[3];
  const float* bk   = (const float*)d_in[4];
  const float* Wv   = (const float*)d_in[5];
  const float* bv   = (const float*)d_in[6];
  const float* Wp   = (const float*)d_in[7];
  const float* bp   = (const float*)d_in[8];
  const float* ln1g = (const float*)d_in[9];
  const float* ln1b = (const float*)d_in[10];
  const float* ln2g = (const float*)d_in[11];
  const float* ln2b = (const float*)d_in[12];
  const float* W1   = (const float*)d_in[13];
  const float* b1   = (const float*)d_in[14];
  const float* W2   = (const float*)d_in[15];
  const float* b2   = (const float*)d_in[16];
  const float* lnfg = (const float*)d_in[17];
  const float* lnfb = (const float*)d_in[18];

  float* x = (float*)d_out;
  char* ws = (char*)d_ws;
  const size_t MB = 1024ull * 1024ull;
  typedef __hip_bfloat16 bf16;
  bf16*  wtqkv = (bf16*)(ws + 0 * MB);    // [3072][1024]
  bf16*  wtp   = (bf16*)(ws + 6 * MB);    // [1024][1024]
  bf16*  wtF1  = (bf16*)(ws + 8 * MB);    // [4096][1024]
  bf16*  wtF2  = (bf16*)(ws + 16 * MB);   // [1024][4096]
  bf16*  hb    = (bf16*)(ws + 24 * MB);   // [4096][1024]
  bf16*  qkv   = (bf16*)(ws + 32 * MB);   // [4096][3072]
  bf16*  mid   = (bf16*)(ws + 56 * MB);   // [4096][4096]
  float* bqkv  = (float*)(ws + 88 * MB);  // [8][3072]
  float* part  = (float*)(ws + 32 * MB);  // W2 split-K partial (qkv region dead
                                          // during FFN; consumed by next ln1)

  hipMemcpyAsync(x, seq, (size_t)M_ * D_ * sizeof(float), hipMemcpyDeviceToDevice, stream);

  const dim3 blk(256);
  const dim3 blkw(512);
  concat_bias<<<96, blk, 0, stream>>>(bq, bk, bv, bqkv);

  for (int i = 0; i < 8; ++i) {
    const size_t wo  = (size_t)i * D_ * D_;
    const size_t vo  = (size_t)i * D_;
    const size_t w1o = (size_t)i * D_ * 4 * D_;

    TrAll ta;
    ta.wq = Wq + wo; ta.wk = Wk + wo; ta.wv = Wv + wo; ta.wp = Wp + wo;
    ta.w1 = W1 + w1o; ta.w2 = W2 + w1o;
    ta.dqkv = wtqkv; ta.dp = wtp; ta.d1 = wtF1; ta.d2 = wtF2;
    // fused ln1 + all weight transposes: 4096 LN rows + 12288 transpose tiles
    if (i == 0)
      ln_tr_fused<false><<<16384, blk, 0, stream>>>(x, nullptr, hb, ln1g + vo, ln1b + vo, ta);
    else
      ln_tr_fused<true><<<16384, blk, 0, stream>>>(x, part, hb, ln1g + vo, ln1b + vo, ta);
    // fused QKV: 128x256 tiles, grid (12,32) = 384 blocks
    gemm_w256<0><<<dim3(12, 32), blkw, 0, stream>>>(
        hb, wtqkv, bqkv + (size_t)i * QSTR_, qkv, nullptr, QSTR_, 1024, 0);
    // attention: QBLK=256, 512 threads, grid (4,16,4)
    attn_mfma<<<dim3(4, 16, 4), blkw, 0, stream>>>(qkv, hb);
    // proj: 128x64 tiles, grid (16,32) = 512 blocks
    gemm_mfma<1, 64><<<dim3(16, 32), blk, 0, stream>>>(hb, wtp, bp + vo, x, 1024, 1024);
    ln_kernel<true, false><<<M_, blk, 0, stream>>>(x, nullptr, hb, ln2g + vo, ln2b + vo);
    // FFN up: 256x256 phase-scheduled, grid (16,16) = 256 blocks, 128KB dyn LDS
    gemm_8ph<<<dim3(16, 16), blkw, 131072, stream>>>(
        hb, wtF1, b1 + (size_t)i * 4096, (unsigned short*)mid, 4096, 1024);
    // FFN down: 128x256 split-K=2, grid (4,32,2) = 256 blocks
    gemm_w256<3><<<dim3(4, 32, 2), blkw, 0, stream>>>(
        mid, wtF2, b2 + vo, x, part, 1024, 4096, 2048);
  }
  ln_kernel<false, true><<<M_, blk, 0, stream>>>(x, part, x, lnfg, lnfb);
}

// Round 20
// 2033.367 us; speedup vs baseline: 1.0084x; 1.0084x over previous
//
#include <hip/hip_runtime.h>
#include <hip/hip_bf16.h>
#include <math.h>

#define B_ 4
#define T_ 1024
#define D_ 1024
#define H_ 16
#define DH_ 64
#define M_ 4096
#define QSTR_ 3072   // fused qkv row stride
#define EPS_ 1e-5f

typedef __attribute__((ext_vector_type(4))) float f32x4;
typedef __attribute__((ext_vector_type(8))) short s16x8;

#if __has_builtin(__builtin_amdgcn_exp2f)
#define EXP2F __builtin_amdgcn_exp2f
#else
#define EXP2F exp2f
#endif

__device__ __forceinline__ float gelu_f(float x) {
  return 0.5f * x * (1.0f + erff(x * 0.70710678118654752f));
}
__device__ __forceinline__ float b2f(unsigned short u) {
  union { unsigned int i; float f; } c; c.i = ((unsigned int)u) << 16; return c.f;
}
__device__ __forceinline__ unsigned short f2b(float f) {
  __hip_bfloat16 h = __float2bfloat16(f);
  return *reinterpret_cast<unsigned short*>(&h);
}
__device__ __forceinline__ void g2l16(void* l, const void* g) {
  __builtin_amdgcn_global_load_lds(
      (const __attribute__((address_space(1))) void*)g,
      (__attribute__((address_space(3))) void*)l, 16, 0, 0);
}

struct TrAll {
  const float *wq, *wk, *wv, *wp, *w1, *w2;
  __hip_bfloat16 *dqkv, *dp, *d1, *d2;
};

// ---------------- LayerNorm body (one 256-thr block per row) ----------------
template<bool BF16OUT, bool ADDP>
__device__ __forceinline__ void ln_body(
    int row, float* __restrict__ xio, const float* __restrict__ part,
    void* __restrict__ out,
    const float* __restrict__ g, const float* __restrict__ b) {
  const int tid = threadIdx.x;
  float* rp = xio + (size_t)row * D_;
  float4 v = *reinterpret_cast<const float4*>(rp + tid * 4);
  if (ADDP) {
    float4 pv = *reinterpret_cast<const float4*>(part + (size_t)row * D_ + tid * 4);
    v.x += pv.x; v.y += pv.y; v.z += pv.z; v.w += pv.w;
    *reinterpret_cast<float4*>(rp + tid * 4) = v;  // write back summed residual
  }
  float s = v.x + v.y + v.z + v.w;
  float s2 = v.x * v.x + v.y * v.y + v.z * v.z + v.w * v.w;
#pragma unroll
  for (int off = 1; off < 64; off <<= 1) {
    s += __shfl_xor(s, off);
    s2 += __shfl_xor(s2, off);
  }
  __shared__ float red[2][4];
  const int wid = tid >> 6;
  if ((tid & 63) == 0) { red[0][wid] = s; red[1][wid] = s2; }
  __syncthreads();
  s = red[0][0] + red[0][1] + red[0][2] + red[0][3];
  s2 = red[1][0] + red[1][1] + red[1][2] + red[1][3];
  const float mu = s * (1.0f / D_);
  const float var = s2 * (1.0f / D_) - mu * mu;
  const float rs = rsqrtf(var + EPS_);
  float4 gv = *reinterpret_cast<const float4*>(g + tid * 4);
  float4 bv = *reinterpret_cast<const float4*>(b + tid * 4);
  float o0 = (v.x - mu) * rs * gv.x + bv.x;
  float o1 = (v.y - mu) * rs * gv.y + bv.y;
  float o2 = (v.z - mu) * rs * gv.z + bv.z;
  float o3 = (v.w - mu) * rs * gv.w + bv.w;
  if (BF16OUT) {
    ushort4 pk;
    pk.x = f2b(o0); pk.y = f2b(o1); pk.z = f2b(o2); pk.w = f2b(o3);
    *reinterpret_cast<ushort4*>((unsigned short*)out + (size_t)row * D_ + tid * 4) = pk;
  } else {
    *reinterpret_cast<float4*>((float*)out + (size_t)row * D_ + tid * 4) =
        make_float4(o0, o1, o2, o3);
  }
}

template<bool BF16OUT, bool ADDP>
__global__ __launch_bounds__(256) void ln_kernel(
    float* __restrict__ xio, const float* __restrict__ part,
    void* __restrict__ out,
    const float* __restrict__ g, const float* __restrict__ b) {
  ln_body<BF16OUT, ADDP>(blockIdx.x, xio, part, out, g, b);
}

// ---------------- transpose tile body ----------------
__device__ __forceinline__ void transpose_tile(
    const float* __restrict__ src, int sld,
    __hip_bfloat16* __restrict__ dst, int dld, int k0, int n0) {
  __shared__ float tile[32][33];
  const int t = threadIdx.x;
  const int r = t >> 3;
  const int cq = (t & 7) * 4;
  float4 vv = *reinterpret_cast<const float4*>(src + (size_t)(k0 + r) * sld + n0 + cq);
  tile[r][cq + 0] = vv.x; tile[r][cq + 1] = vv.y;
  tile[r][cq + 2] = vv.z; tile[r][cq + 3] = vv.w;
  __syncthreads();
  ushort4 o;
  o.x = f2b(tile[cq + 0][r]); o.y = f2b(tile[cq + 1][r]);
  o.z = f2b(tile[cq + 2][r]); o.w = f2b(tile[cq + 3][r]);
  *reinterpret_cast<ushort4*>((unsigned short*)dst + (size_t)(n0 + r) * dld + k0 + cq) = o;
}

__device__ __forceinline__ void transpose_dispatch(int t, const TrAll& a) {
  const float* src;
  __hip_bfloat16* dst;
  int sld, dld, k0, n0;
  if (t < 4096) {
    const int m = t >> 10, tile = t & 1023;
    k0 = (tile >> 5) * 32; n0 = (tile & 31) * 32;
    src = (m == 0) ? a.wq : (m == 1) ? a.wk : (m == 2) ? a.wv : a.wp;
    sld = 1024; dld = 1024;
    dst = (m < 3) ? (a.dqkv + (size_t)m * 1024 * 1024) : a.dp;
  } else if (t < 8192) {
    const int tile = t - 4096;
    k0 = (tile & 31) * 32; n0 = (tile >> 5) * 32;
    src = a.w1; sld = 4096; dst = a.d1; dld = 1024;
  } else {
    const int tile = t - 8192;
    k0 = (tile >> 5) * 32; n0 = (tile & 31) * 32;
    src = a.w2; sld = 1024; dst = a.d2; dld = 4096;
  }
  transpose_tile(src, sld, dst, dld, k0, n0);
}

// ---------------- fused: ln1 (rows 0..4095) + all weight transposes ----------------
template<bool ADDP>
__global__ __launch_bounds__(256) void ln_tr_fused(
    float* __restrict__ xio, const float* __restrict__ part,
    void* __restrict__ out,
    const float* __restrict__ g, const float* __restrict__ b, TrAll a) {
  if (blockIdx.x < M_) {
    ln_body<true, ADDP>(blockIdx.x, xio, part, out, g, b);
  } else {
    transpose_dispatch(blockIdx.x - M_, a);
  }
}

// ---------------- bias concat: [L][3072] <- bq|bk|bv ----------------
__global__ __launch_bounds__(256) void concat_bias(
    const float* __restrict__ bq, const float* __restrict__ bk,
    const float* __restrict__ bv, float* __restrict__ out) {
  const int i = blockIdx.x * 256 + threadIdx.x;
  const int l = i / QSTR_, c = i % QSTR_;
  const float* src = (c < 1024) ? bq : ((c < 2048) ? bk : bv);
  out[i] = src[l * 1024 + (c & 1023)];
}

// ---------------- bf16 MFMA GEMM 128xBN (4 waves): 3-deep pipeline + swizzle ----
// MODE 0: store bf16; MODE 1: fp32 C += result; MODE 2: store bf16 gelu(result)
template<int MODE, int BN>
__global__ __launch_bounds__(256) void gemm_mfma(
    const __hip_bfloat16* __restrict__ A,
    const __hip_bfloat16* __restrict__ Bt,
    const float* __restrict__ bias,
    void* __restrict__ Cout, int N, int K) {
  __shared__ short As[3][128 * 32];
  __shared__ short Bs[3][BN * 32];
  int bid = blockIdx.y * gridDim.x + blockIdx.x;
  const int nwg = gridDim.x * gridDim.y;
  bid = (bid & 7) * (nwg >> 3) + (bid >> 3);
  const int gn = (bid % gridDim.x) * BN;
  const int gm = (bid / gridDim.x) * 128;

  const int tid = threadIdx.x;
  const int wid = tid >> 6, lane = tid & 63;
  constexpr int MR = (BN == 128) ? 4 : 2;
  const int wm = (BN == 128) ? (wid >> 1) : wid;
  const int wn = (BN == 128) ? (wid & 1) : 0;
  const int fr = lane & 15, kg = lane >> 4;

  const int ldr = lane >> 2;
  const int ldk = (((lane & 3) ^ ((lane >> 3) & 3)) * 8);  // pre-swizzled source chunk
  const unsigned short* ap =
      (const unsigned short*)A + (size_t)(gm + wid * 32 + ldr) * K + ldk;
  const unsigned short* bp =
      (const unsigned short*)Bt +
      (size_t)(gn + ((BN == 128) ? wid * 32 : wid * 16) + ldr) * K + ldk;

  const int nkt = K >> 5;

#define STAGE_T(t, buf)                                                    \
  {                                                                        \
    const unsigned short* a_ = ap + (size_t)(t) * 32;                      \
    g2l16((char*)As[buf] + (wid * 2) * 1024, a_);                          \
    g2l16((char*)As[buf] + (wid * 2 + 1) * 1024, a_ + (size_t)16 * K);     \
    const unsigned short* b_ = bp + (size_t)(t) * 32;                      \
    if (BN == 128) {                                                       \
      g2l16((char*)Bs[buf] + (wid * 2) * 1024, b_);                        \
      g2l16((char*)Bs[buf] + (wid * 2 + 1) * 1024, b_ + (size_t)16 * K);   \
    } else {                                                               \
      g2l16((char*)Bs[buf] + wid * 1024, b_);                              \
    }                                                                      \
  }

  STAGE_T(0, 0);
  STAGE_T(1, 1);

  const int cxa = (kg ^ ((fr >> 1) & 3)) * 8;  // swizzled read chunk (shorts)
  f32x4 acc[MR][4] = {};
  for (int t = 0; t < nkt; ++t) {
    const int buf = t % 3;
    if (t + 2 < nkt) STAGE_T(t + 2, (t + 2) % 3);
    const int rem = nkt - 1 - t;
    if (rem >= 2) {
      if (BN == 128) asm volatile("s_waitcnt vmcnt(8)" ::: "memory");
      else           asm volatile("s_waitcnt vmcnt(6)" ::: "memory");
    } else if (rem == 1) {
      if (BN == 128) asm volatile("s_waitcnt vmcnt(4)" ::: "memory");
      else           asm volatile("s_waitcnt vmcnt(3)" ::: "memory");
    } else {
      asm volatile("s_waitcnt vmcnt(0)" ::: "memory");
    }
    __builtin_amdgcn_s_barrier();
    __builtin_amdgcn_sched_barrier(0);
    s16x8 af[MR], bfr[4];
#pragma unroll
    for (int m = 0; m < MR; ++m)
      af[m] = *reinterpret_cast<const s16x8*>(
          &As[buf][(wm * (16 * MR) + m * 16 + fr) * 32 + cxa]);
#pragma unroll
    for (int n = 0; n < 4; ++n)
      bfr[n] = *reinterpret_cast<const s16x8*>(
          &Bs[buf][(wn * 64 + n * 16 + fr) * 32 + cxa]);
#pragma unroll
    for (int m = 0; m < MR; ++m)
#pragma unroll
      for (int n = 0; n < 4; ++n)
        acc[m][n] = __builtin_amdgcn_mfma_f32_16x16x32_bf16(af[m], bfr[n], acc[m][n], 0, 0, 0);
    __builtin_amdgcn_sched_barrier(0);
    __builtin_amdgcn_s_barrier();
  }
#undef STAGE_T

  const int r0 = gm + wm * (16 * MR);
  const int c0 = gn + wn * 64;
  float bb[4];
#pragma unroll
  for (int n = 0; n < 4; ++n)
    bb[n] = bias ? bias[c0 + n * 16 + fr] : 0.0f;
#pragma unroll
  for (int m = 0; m < MR; ++m) {
#pragma unroll
    for (int j = 0; j < 4; ++j) {
      const int row = r0 + m * 16 + kg * 4 + j;
#pragma unroll
      for (int n = 0; n < 4; ++n) {
        float val = acc[m][n][j] + bb[n];
        const size_t idx = (size_t)row * N + c0 + n * 16 + fr;
        if (MODE == 0) {
          ((unsigned short*)Cout)[idx] = f2b(val);
        } else if (MODE == 1) {
          float* cp = (float*)Cout + idx;
          *cp = *cp + val;
        } else {
          ((unsigned short*)Cout)[idx] = f2b(gelu_f(val));
        }
      }
    }
  }
}

// ------- 128x256 wide GEMM (8 waves, 512 thr): halves B-side cache traffic -------
// MODE: 0 store bf16; 1 fp32 +=; 2 gelu bf16; 3 split-K (z0: X+=acc+bias, z1: P=acc)
template<int MODE>
__global__ __launch_bounds__(512) void gemm_w256(
    const __hip_bfloat16* __restrict__ A,
    const __hip_bfloat16* __restrict__ Bt,
    const float* __restrict__ bias,
    void* __restrict__ Cout, float* __restrict__ P,
    int N, int K, int KS) {
  __shared__ short As[3][128 * 32];
  __shared__ short Bs[3][256 * 32];
  int bid = blockIdx.y * gridDim.x + blockIdx.x;
  const int nwg = gridDim.x * gridDim.y;
  bid = (bid & 7) * (nwg >> 3) + (bid >> 3);
  const int gn = (bid % gridDim.x) * 256;
  const int gm = (bid / gridDim.x) * 128;
  const int koff = (MODE == 3) ? blockIdx.z * KS : 0;

  const int tid = threadIdx.x;
  const int wid = tid >> 6, lane = tid & 63;
  const int wm = wid & 1, wn = wid >> 1;  // 2 x 4 waves of 64x64
  const int fr = lane & 15, kg = lane >> 4;

  const int ldr = lane >> 2;
  const int ldk = (((lane & 3) ^ ((lane >> 3) & 3)) * 8);
  const unsigned short* ap =
      (const unsigned short*)A + (size_t)(gm + wid * 16 + ldr) * K + koff + ldk;
  const unsigned short* bp =
      (const unsigned short*)Bt + (size_t)(gn + wid * 32 + ldr) * K + koff + ldk;

  const int nkt = ((MODE == 3) ? KS : K) >> 5;

#define STAGE_W(t, buf)                                                    \
  {                                                                        \
    g2l16((char*)As[buf] + wid * 1024, ap + (size_t)(t) * 32);             \
    const unsigned short* b_ = bp + (size_t)(t) * 32;                      \
    g2l16((char*)Bs[buf] + (wid * 2) * 1024, b_);                          \
    g2l16((char*)Bs[buf] + (wid * 2 + 1) * 1024, b_ + (size_t)16 * K);     \
  }

  STAGE_W(0, 0);
  STAGE_W(1, 1);

  const int cxa = (kg ^ ((fr >> 1) & 3)) * 8;
  f32x4 acc[4][4] = {};
  for (int t = 0; t < nkt; ++t) {
    const int buf = t % 3;
    if (t + 2 < nkt) STAGE_W(t + 2, (t + 2) % 3);
    const int rem = nkt - 1 - t;
    if (rem >= 2)      asm volatile("s_waitcnt vmcnt(6)" ::: "memory");
    else if (rem == 1) asm volatile("s_waitcnt vmcnt(3)" ::: "memory");
    else               asm volatile("s_waitcnt vmcnt(0)" ::: "memory");
    __builtin_amdgcn_s_barrier();
    __builtin_amdgcn_sched_barrier(0);
    s16x8 af[4], bfr[4];
#pragma unroll
    for (int m = 0; m < 4; ++m)
      af[m] = *reinterpret_cast<const s16x8*>(
          &As[buf][(wm * 64 + m * 16 + fr) * 32 + cxa]);
#pragma unroll
    for (int n = 0; n < 4; ++n)
      bfr[n] = *reinterpret_cast<const s16x8*>(
          &Bs[buf][(wn * 64 + n * 16 + fr) * 32 + cxa]);
#pragma unroll
    for (int m = 0; m < 4; ++m)
#pragma unroll
      for (int n = 0; n < 4; ++n)
        acc[m][n] = __builtin_amdgcn_mfma_f32_16x16x32_bf16(af[m], bfr[n], acc[m][n], 0, 0, 0);
    __builtin_amdgcn_sched_barrier(0);
    __builtin_amdgcn_s_barrier();
  }
#undef STAGE_W

  const int r0 = gm + wm * 64;
  const int c0 = gn + wn * 64;
  if (MODE == 3 && blockIdx.z == 1) {
#pragma unroll
    for (int m = 0; m < 4; ++m)
#pragma unroll
      for (int j = 0; j < 4; ++j) {
        const int row = r0 + m * 16 + kg * 4 + j;
#pragma unroll
        for (int n = 0; n < 4; ++n)
          P[(size_t)row * N + c0 + n * 16 + fr] = acc[m][n][j];
      }
    return;
  }
  float bb[4];
#pragma unroll
  for (int n = 0; n < 4; ++n)
    bb[n] = bias ? bias[c0 + n * 16 + fr] : 0.0f;
#pragma unroll
  for (int m = 0; m < 4; ++m) {
#pragma unroll
    for (int j = 0; j < 4; ++j) {
      const int row = r0 + m * 16 + kg * 4 + j;
#pragma unroll
      for (int n = 0; n < 4; ++n) {
        float val = acc[m][n][j] + bb[n];
        const size_t idx = (size_t)row * N + c0 + n * 16 + fr;
        if (MODE == 0) {
          ((unsigned short*)Cout)[idx] = f2b(val);
        } else if (MODE == 1 || MODE == 3) {
          float* cp = (float*)Cout + idx;
          *cp = *cp + val;
        } else {
          ((unsigned short*)Cout)[idx] = f2b(gelu_f(val));
        }
      }
    }
  }
}

// ------- 256x256 phase-scheduled GEMM (8 waves, BK=64, 128KB dynamic LDS) -------
__global__ __launch_bounds__(512) void gemm_8ph(
    const __hip_bfloat16* __restrict__ A,
    const __hip_bfloat16* __restrict__ Bt,
    const float* __restrict__ bias,
    unsigned short* __restrict__ Cout, int N, int K) {
  extern __shared__ short sm8[];  // 2 halves x (A 256x64 + B 256x64) = 128KB
  int bid = blockIdx.y * gridDim.x + blockIdx.x;
  const int nwg = gridDim.x * gridDim.y;
  bid = (bid & 7) * (nwg >> 3) + (bid >> 3);
  const int gn = (bid % gridDim.x) * 256;
  const int gm = (bid / gridDim.x) * 256;
  const int tid = threadIdx.x;
  const int wid = tid >> 6, lane = tid & 63;
  const int wm = wid >> 2, wn = wid & 3;   // 2m x 4n
  const int fr = lane & 15, kg = lane >> 4;
  const int r8 = lane >> 3, cp = lane & 7;
  const unsigned short* Ap = (const unsigned short*)A;
  const unsigned short* Bp = (const unsigned short*)Bt;
  const int nkt = K >> 6;

#define STAGE8(t, hbase, u)                                                  \
  {                                                                          \
    const int row_ = (u) * 64 + wid * 8 + r8;                                \
    const int c16_ = cp ^ (row_ & 7);                                        \
    g2l16((hbase) + ((u) * 64 + wid * 8) * 128,                              \
          Ap + (size_t)(gm + row_) * K + (size_t)(t) * 64 + c16_ * 8);       \
    g2l16((hbase) + 32768 + ((u) * 64 + wid * 8) * 128,                      \
          Bp + (size_t)(gn + row_) * K + (size_t)(t) * 64 + c16_ * 8);       \
  }

#pragma unroll
  for (int u = 0; u < 4; ++u) STAGE8(0, (char*)sm8, u);
  asm volatile("s_waitcnt vmcnt(0)" ::: "memory");
  __builtin_amdgcn_s_barrier();

  f32x4 acc[8][4] = {};
  for (int t = 0; t < nkt; ++t) {
    char* cur = (char*)sm8 + (t & 1) * 65536;
    char* nxt = (char*)sm8 + ((t & 1) ^ 1) * 65536;
    __builtin_amdgcn_sched_barrier(0);
#pragma unroll
    for (int p = 0; p < 4; ++p) {
      if (t + 1 < nkt) STAGE8(t + 1, nxt, p);
      s16x8 af[2][2], bfr[4][2];
#pragma unroll
      for (int mm = 0; mm < 2; ++mm) {
        const int row = wm * 128 + (p * 2 + mm) * 16 + fr;
#pragma unroll
        for (int kk = 0; kk < 2; ++kk)
          af[mm][kk] = *reinterpret_cast<const s16x8*>(
              cur + row * 128 + (((kk * 4 + kg) ^ (row & 7)) << 4));
      }
#pragma unroll
      for (int n = 0; n < 4; ++n) {
        const int row = wn * 64 + n * 16 + fr;
#pragma unroll
        for (int kk = 0; kk < 2; ++kk)
          bfr[n][kk] = *reinterpret_cast<const s16x8*>(
              cur + 32768 + row * 128 + (((kk * 4 + kg) ^ (row & 7)) << 4));
      }
      __builtin_amdgcn_s_setprio(1);
#pragma unroll
      for (int kk = 0; kk < 2; ++kk)
#pragma unroll
        for (int mm = 0; mm < 2; ++mm)
#pragma unroll
          for (int n = 0; n < 4; ++n)
            acc[p * 2 + mm][n] = __builtin_amdgcn_mfma_f32_16x16x32_bf16(
                af[mm][kk], bfr[n][kk], acc[p * 2 + mm][n], 0, 0, 0);
      __builtin_amdgcn_s_setprio(0);
    }
    if (t + 1 < nkt) {
      asm volatile("s_waitcnt vmcnt(0)" ::: "memory");
      __builtin_amdgcn_s_barrier();
    }
  }
#undef STAGE8

  const int r0 = gm + wm * 128;
  const int c0 = gn + wn * 64;
  float bb[4];
#pragma unroll
  for (int n = 0; n < 4; ++n) bb[n] = bias[c0 + n * 16 + fr];
#pragma unroll
  for (int m = 0; m < 8; ++m)
#pragma unroll
    for (int j = 0; j < 4; ++j) {
      const int row = r0 + m * 16 + kg * 4 + j;
#pragma unroll
      for (int n = 0; n < 4; ++n)
        Cout[(size_t)row * N + c0 + n * 16 + fr] =
            f2b(gelu_f(acc[m][n][j] + bb[n]));
    }
}

// ---------------- MFMA flash attention v8: QBLK=256, single barrier per visit ----
// Ks[3] prefetch ring + Vt[2] double-buffer make sync_a removable: between
// barrier(kt) and barrier(kt+1), compute(kt) reads Ks[kt%3]/Vt[kt&1] while the
// next iteration writes Vt[(kt+1)&1] and Ks[(kt+2)%3] - disjoint. Each wave's
// vmcnt(0) precedes its barrier, so after the barrier all K(kt)/V(kt) visible.
__global__ __launch_bounds__(512) void attn_mfma(
    const __hip_bfloat16* __restrict__ qkv, __hip_bfloat16* __restrict__ yg) {
  const int x = blockIdx.x;
  const int qb = (x < 2) ? (3 - x) : (x - 2);  // balanced pairing (3,0),(2,1)
  const int hh = blockIdx.y;
  const int bb = blockIdx.z;
  __shared__ short Qs[256 * 64];    // Q staging, then P (32KB)
  __shared__ short Ks[3][64 * 64];  // 24KB prefetch ring
  __shared__ short Vt[2][64 * 64];  // 16KB double buffer
  const int tid = threadIdx.x;
  const int wid = tid >> 6, lane = tid & 63;
  const int fr = lane & 15, kg = lane >> 4;
  const size_t qb_base = (size_t)bb * T_ * QSTR_ + (size_t)hh * DH_;
  const unsigned short* qgp = (const unsigned short*)qkv + qb_base;
  const unsigned short* kgp = qgp + 1024;
  const unsigned short* vgp = qgp + 2048;
  const float C = 0.125f * 1.4426950408889634f;  // scale * log2(e)

  const int r8 = lane >> 3, cp = lane & 7;
#pragma unroll
  for (int u = 0; u < 4; ++u) {
    const int row = wid * 32 + u * 8 + r8;
    const int c16 = cp ^ (row & 7);
    g2l16((char*)Qs + (wid * 32 + u * 8) * 128,
          qgp + (size_t)(qb * 256 + row) * QSTR_ + c16 * 8);
  }
  {
    const int row = wid * 8 + r8;
    const int c16 = cp ^ (row & 7);
    g2l16((char*)Ks[0] + (wid * 8) * 128, kgp + (size_t)row * QSTR_ + c16 * 8);
  }
  const int kv0 = tid >> 3;
  const int d0 = (tid & 7) * 8;
  const int rot = tid & 7;
  s16x8 sva = *reinterpret_cast<const s16x8*>(vgp + (size_t)kv0 * QSTR_ + d0);

  asm volatile("s_waitcnt vmcnt(0)" ::: "memory");
  __syncthreads();
  s16x8 qf[2][2];
#pragma unroll
  for (int rg = 0; rg < 2; ++rg) {
    const int row = wid * 32 + rg * 16 + fr;
    const char* rp = (const char*)Qs + row * 128;
    qf[rg][0] = *reinterpret_cast<const s16x8*>(rp + (((0 + kg) ^ (row & 7)) << 4));
    qf[rg][1] = *reinterpret_cast<const s16x8*>(rp + (((4 + kg) ^ (row & 7)) << 4));
  }

  f32x4 acco[2][4] = {};
  float m_run[2] = {-INFINITY, -INFINITY};
  float l_run[2] = {0.f, 0.f};

  const int q16hi = qb * 16 + wid * 2 + 1;
  const int ntile = 4 * qb + 4;
  for (int kt = 0; kt < ntile; ++kt) {
    const int kb3 = kt % 3;
    const int vb = kt & 1;
    asm volatile("s_waitcnt vmcnt(0)" ::: "memory");  // own K(kt)/V(kt) loads done
    // ---- scatter V(kt) regs -> Vt[vb] (swizzled transpose) ----
#pragma unroll
    for (int j = 0; j < 8; ++j) {
      const int jj = (j + rot) & 7;
      const int d = d0 + jj;
      *(short*)((char*)Vt[vb] + d * 128 + ((((kv0 >> 3) ^ jj) & 7) << 4) + (kv0 & 7) * 2) = sva[jj];
    }
    // ---- prefetch tile kt+1 (K into ring slot (kt+1)%3; V into regs) ----
    if (kt + 1 < ntile) {
      const int row = wid * 8 + r8;
      const int c16 = cp ^ (row & 7);
      g2l16((char*)Ks[(kt + 1) % 3] + (wid * 8) * 128,
            kgp + (size_t)((kt + 1) * 64 + row) * QSTR_ + c16 * 8);
      sva = *reinterpret_cast<const s16x8*>(
          vgp + (size_t)((kt + 1) * 64 + kv0) * QSTR_ + d0);
    }
    __syncthreads();  // single barrier: V(kt) scatter + all waves' K(kt) visible
    __builtin_amdgcn_sched_barrier(0);

    if (kt * 4 <= q16hi) {
      f32x4 accs[2][4] = {};
      __builtin_amdgcn_s_setprio(1);
#pragma unroll
      for (int n = 0; n < 4; ++n) {
        const int row = n * 16 + fr;
        const char* rp = (const char*)Ks[kb3] + row * 128;
        s16x8 kf0 = *reinterpret_cast<const s16x8*>(rp + (((0 + kg) ^ (row & 7)) << 4));
        s16x8 kf1 = *reinterpret_cast<const s16x8*>(rp + (((4 + kg) ^ (row & 7)) << 4));
#pragma unroll
        for (int rg = 0; rg < 2; ++rg) {
          accs[rg][n] = __builtin_amdgcn_mfma_f32_16x16x32_bf16(kf0, qf[rg][0], accs[rg][n], 0, 0, 0);
          accs[rg][n] = __builtin_amdgcn_mfma_f32_16x16x32_bf16(kf1, qf[rg][1], accs[rg][n], 0, 0, 0);
        }
      }
      __builtin_amdgcn_s_setprio(0);
      float aj[2][4];
#pragma unroll
      for (int rg = 0; rg < 2; ++rg) {
        const int q16 = qb * 16 + wid * 2 + rg;
        float mloc = -3.0e38f;
#pragma unroll
        for (int n = 0; n < 4; ++n)
          if (kt * 4 + n <= q16)
#pragma unroll
            for (int j = 0; j < 4; ++j) mloc = fmaxf(mloc, accs[rg][n][j]);
        mloc = fmaxf(mloc, __shfl_xor(mloc, 16));
        mloc = fmaxf(mloc, __shfl_xor(mloc, 32));
        const float mn = fmaxf(m_run[rg], mloc);
        const float a_ = EXP2F((m_run[rg] - mn) * C);
        m_run[rg] = mn;
        const int prow = wid * 32 + rg * 16 + fr;
        char* pbase = (char*)Qs + prow * 128 + (kg & 1) * 8;
        const int rxor = prow & 7;
        float psum = 0.f;
#pragma unroll
        for (int n = 0; n < 4; ++n) {
          const bool dead = (kt * 4 + n > q16);
          unsigned long long pk = 0;
#pragma unroll
          for (int j = 0; j < 4; ++j) {
            const float p = dead ? 0.0f : EXP2F((accs[rg][n][j] - mn) * C);
            psum += p;
            pk |= (unsigned long long)f2b(p) << (16 * j);
          }
          *reinterpret_cast<unsigned long long*>(
              pbase + (((n * 2 + (kg >> 1)) ^ rxor) << 4)) = pk;
        }
        l_run[rg] = l_run[rg] * a_ + psum;
#pragma unroll
        for (int j = 0; j < 4; ++j) aj[rg][j] = __shfl(a_, kg * 4 + j);
#pragma unroll
        for (int dt = 0; dt < 4; ++dt)
#pragma unroll
          for (int j = 0; j < 4; ++j) acco[rg][dt][j] *= aj[rg][j];
      }
      __builtin_amdgcn_s_setprio(1);
#pragma unroll
      for (int rg = 0; rg < 2; ++rg) {
        const int prow = wid * 32 + rg * 16 + fr;
        const char* pp = (const char*)Qs + prow * 128;
#pragma unroll
        for (int kk = 0; kk < 2; ++kk) {
          const s16x8 pf = *reinterpret_cast<const s16x8*>(
              pp + ((((kk * 4 + kg) ^ (prow & 7)) & 7) << 4));
#pragma unroll
          for (int dt = 0; dt < 4; ++dt) {
            const int vrow = dt * 16 + fr;
            const s16x8 vf = *reinterpret_cast<const s16x8*>(
                (const char*)Vt[vb] + vrow * 128 + ((((kk * 4 + kg) ^ (vrow & 7)) & 7) << 4));
            acco[rg][dt] = __builtin_amdgcn_mfma_f32_16x16x32_bf16(pf, vf, acco[rg][dt], 0, 0, 0);
          }
        }
      }
      __builtin_amdgcn_s_setprio(0);
    }
  }

  unsigned short* yp = (unsigned short*)yg + (size_t)bb * T_ * D_ + (size_t)hh * DH_;
#pragma unroll
  for (int rg = 0; rg < 2; ++rg) {
    float lt = l_run[rg];
    lt += __shfl_xor(lt, 16);
    lt += __shfl_xor(lt, 32);
    const float linv = 1.0f / lt;
    float lj[4];
#pragma unroll
    for (int j = 0; j < 4; ++j) lj[j] = __shfl(linv, kg * 4 + j);
#pragma unroll
    for (int dt = 0; dt < 4; ++dt)
#pragma unroll
      for (int j = 0; j < 4; ++j) {
        const int row = qb * 256 + wid * 32 + rg * 16 + kg * 4 + j;
        yp[(size_t)row * D_ + dt * 16 + fr] = f2b(acco[rg][dt][j] * lj[j]);
      }
  }
}

extern "C" void kernel_launch(void* const* d_in, const int* in_sizes, int n_in,
                              void* d_out, int out_size, void* d_ws, size_t ws_size,
                              hipStream_t stream) {
  (void)in_sizes; (void)n_in; (void)out_size; (void)ws_size;
  const float* seq  = (const float*)d_in[0];
  const float* Wq   = (const float*)d_in[1];
  const float* bq   = (const float*)d_in[2];
  const float* Wk   = (const float*)d_in[3];
  const float* bk   = (const float*)d_in[4];
  const float* Wv   = (const float*)d_in[5];
  const float* bv   = (const float*)d_in[6];
  const float* Wp   = (const float*)d_in[7];
  const float* bp   = (const float*)d_in[8];
  const float* ln1g = (const float*)d_in[9];
  const float* ln1b = (const float*)d_in[10];
  const float* ln2g = (const float*)d_in[11];
  const float* ln2b = (const float*)d_in[12];
  const float* W1   = (const float*)d_in[13];
  const float* b1   = (const float*)d_in[14];
  const float* W2   = (const float*)d_in[15];
  const float* b2   = (const float*)d_in[16];
  const float* lnfg = (const float*)d_in[17];
  const float* lnfb = (const float*)d_in[18];

  float* x = (float*)d_out;
  char* ws = (char*)d_ws;
  const size_t MB = 1024ull * 1024ull;
  typedef __hip_bfloat16 bf16;
  bf16*  wtqkv = (bf16*)(ws + 0 * MB);    // [3072][1024]
  bf16*  wtp   = (bf16*)(ws + 6 * MB);    // [1024][1024]
  bf16*  wtF1  = (bf16*)(ws + 8 * MB);    // [4096][1024]
  bf16*  wtF2  = (bf16*)(ws + 16 * MB);   // [1024][4096]
  bf16*  hb    = (bf16*)(ws + 24 * MB);   // [4096][1024]
  bf16*  qkv   = (bf16*)(ws + 32 * MB);   // [4096][3072]
  bf16*  mid   = (bf16*)(ws + 56 * MB);   // [4096][4096]
  float* bqkv  = (float*)(ws + 88 * MB);  // [8][3072]
  float* part  = (float*)(ws + 32 * MB);  // W2 split-K partial (qkv region dead
                                          // during FFN; consumed by next ln1)

  hipMemcpyAsync(x, seq, (size_t)M_ * D_ * sizeof(float), hipMemcpyDeviceToDevice, stream);

  const dim3 blk(256);
  const dim3 blkw(512);
  concat_bias<<<96, blk, 0, stream>>>(bq, bk, bv, bqkv);

  for (int i = 0; i < 8; ++i) {
    const size_t wo  = (size_t)i * D_ * D_;
    const size_t vo  = (size_t)i * D_;
    const size_t w1o = (size_t)i * D_ * 4 * D_;

    TrAll ta;
    ta.wq = Wq + wo; ta.wk = Wk + wo; ta.wv = Wv + wo; ta.wp = Wp + wo;
    ta.w1 = W1 + w1o; ta.w2 = W2 + w1o;
    ta.dqkv = wtqkv; ta.dp = wtp; ta.d1 = wtF1; ta.d2 = wtF2;
    // fused ln1 + all weight transposes: 4096 LN rows + 12288 transpose tiles
    if (i == 0)
      ln_tr_fused<false><<<16384, blk, 0, stream>>>(x, nullptr, hb, ln1g + vo, ln1b + vo, ta);
    else
      ln_tr_fused<true><<<16384, blk, 0, stream>>>(x, part, hb, ln1g + vo, ln1b + vo, ta);
    // fused QKV: 128x256 tiles, grid (12,32) = 384 blocks
    gemm_w256<0><<<dim3(12, 32), blkw, 0, stream>>>(
        hb, wtqkv, bqkv + (size_t)i * QSTR_, qkv, nullptr, QSTR_, 1024, 0);
    // attention: QBLK=256, 512 threads, grid (4,16,4)
    attn_mfma<<<dim3(4, 16, 4), blkw, 0, stream>>>(qkv, hb);
    // proj: 128x64 tiles, grid (16,32) = 512 blocks
    gemm_mfma<1, 64><<<dim3(16, 32), blk, 0, stream>>>(hb, wtp, bp + vo, x, 1024, 1024);
    ln_kernel<true, false><<<M_, blk, 0, stream>>>(x, nullptr, hb, ln2g + vo, ln2b + vo);
    // FFN up: 256x256 phase-scheduled, grid (16,16) = 256 blocks, 128KB dyn LDS
    gemm_8ph<<<dim3(16, 16), blkw, 131072, stream>>>(
        hb, wtF1, b1 + (size_t)i * 4096, (unsigned short*)mid, 4096, 1024);
    // FFN down: 128x256 split-K=2, grid (4,32,2) = 256 blocks
    gemm_w256<3><<<dim3(4, 32, 2), blkw, 0, stream>>>(
        mid, wtF2, b2 + vo, x, part, 1024, 4096, 2048);
  }
  ln_kernel<false, true><<<M_, blk, 0, stream>>>(x, part, x, lnfg, lnfb);
}

// Round 21
// 2016.562 us; speedup vs baseline: 1.0168x; 1.0083x over previous
//
#include <hip/hip_runtime.h>
#include <hip/hip_bf16.h>
#include <math.h>

#define B_ 4
#define T_ 1024
#define D_ 1024
#define H_ 16
#define DH_ 64
#define M_ 4096
#define QSTR_ 3072   // fused qkv row stride
#define EPS_ 1e-5f

typedef __attribute__((ext_vector_type(4))) float f32x4;
typedef __attribute__((ext_vector_type(8))) short s16x8;

#if __has_builtin(__builtin_amdgcn_exp2f)
#define EXP2F __builtin_amdgcn_exp2f
#else
#define EXP2F exp2f
#endif

__device__ __forceinline__ float gelu_f(float x) {
  return 0.5f * x * (1.0f + erff(x * 0.70710678118654752f));
}
__device__ __forceinline__ float b2f(unsigned short u) {
  union { unsigned int i; float f; } c; c.i = ((unsigned int)u) << 16; return c.f;
}
__device__ __forceinline__ unsigned short f2b(float f) {
  __hip_bfloat16 h = __float2bfloat16(f);
  return *reinterpret_cast<unsigned short*>(&h);
}
__device__ __forceinline__ void g2l16(void* l, const void* g) {
  __builtin_amdgcn_global_load_lds(
      (const __attribute__((address_space(1))) void*)g,
      (__attribute__((address_space(3))) void*)l, 16, 0, 0);
}

struct TrAll {
  const float *wq, *wk, *wv, *wp, *w1, *w2;
  __hip_bfloat16 *dqkv, *dp, *d1, *d2;
};

// ---------------- LayerNorm body (one 256-thr block per row) ----------------
template<bool BF16OUT, bool ADDP>
__device__ __forceinline__ void ln_body(
    int row, float* __restrict__ xio, const float* __restrict__ part,
    void* __restrict__ out,
    const float* __restrict__ g, const float* __restrict__ b) {
  const int tid = threadIdx.x;
  float* rp = xio + (size_t)row * D_;
  float4 v = *reinterpret_cast<const float4*>(rp + tid * 4);
  if (ADDP) {
    float4 pv = *reinterpret_cast<const float4*>(part + (size_t)row * D_ + tid * 4);
    v.x += pv.x; v.y += pv.y; v.z += pv.z; v.w += pv.w;
    *reinterpret_cast<float4*>(rp + tid * 4) = v;  // write back summed residual
  }
  float s = v.x + v.y + v.z + v.w;
  float s2 = v.x * v.x + v.y * v.y + v.z * v.z + v.w * v.w;
#pragma unroll
  for (int off = 1; off < 64; off <<= 1) {
    s += __shfl_xor(s, off);
    s2 += __shfl_xor(s2, off);
  }
  __shared__ float red[2][4];
  const int wid = tid >> 6;
  if ((tid & 63) == 0) { red[0][wid] = s; red[1][wid] = s2; }
  __syncthreads();
  s = red[0][0] + red[0][1] + red[0][2] + red[0][3];
  s2 = red[1][0] + red[1][1] + red[1][2] + red[1][3];
  const float mu = s * (1.0f / D_);
  const float var = s2 * (1.0f / D_) - mu * mu;
  const float rs = rsqrtf(var + EPS_);
  float4 gv = *reinterpret_cast<const float4*>(g + tid * 4);
  float4 bv = *reinterpret_cast<const float4*>(b + tid * 4);
  float o0 = (v.x - mu) * rs * gv.x + bv.x;
  float o1 = (v.y - mu) * rs * gv.y + bv.y;
  float o2 = (v.z - mu) * rs * gv.z + bv.z;
  float o3 = (v.w - mu) * rs * gv.w + bv.w;
  if (BF16OUT) {
    ushort4 pk;
    pk.x = f2b(o0); pk.y = f2b(o1); pk.z = f2b(o2); pk.w = f2b(o3);
    *reinterpret_cast<ushort4*>((unsigned short*)out + (size_t)row * D_ + tid * 4) = pk;
  } else {
    *reinterpret_cast<float4*>((float*)out + (size_t)row * D_ + tid * 4) =
        make_float4(o0, o1, o2, o3);
  }
}

template<bool BF16OUT, bool ADDP>
__global__ __launch_bounds__(256) void ln_kernel(
    float* __restrict__ xio, const float* __restrict__ part,
    void* __restrict__ out,
    const float* __restrict__ g, const float* __restrict__ b) {
  ln_body<BF16OUT, ADDP>(blockIdx.x, xio, part, out, g, b);
}

// ---------------- transpose tile body ----------------
__device__ __forceinline__ void transpose_tile(
    const float* __restrict__ src, int sld,
    __hip_bfloat16* __restrict__ dst, int dld, int k0, int n0) {
  __shared__ float tile[32][33];
  const int t = threadIdx.x;
  const int r = t >> 3;
  const int cq = (t & 7) * 4;
  float4 vv = *reinterpret_cast<const float4*>(src + (size_t)(k0 + r) * sld + n0 + cq);
  tile[r][cq + 0] = vv.x; tile[r][cq + 1] = vv.y;
  tile[r][cq + 2] = vv.z; tile[r][cq + 3] = vv.w;
  __syncthreads();
  ushort4 o;
  o.x = f2b(tile[cq + 0][r]); o.y = f2b(tile[cq + 1][r]);
  o.z = f2b(tile[cq + 2][r]); o.w = f2b(tile[cq + 3][r]);
  *reinterpret_cast<ushort4*>((unsigned short*)dst + (size_t)(n0 + r) * dld + k0 + cq) = o;
}

__device__ __forceinline__ void transpose_dispatch(int t, const TrAll& a) {
  const float* src;
  __hip_bfloat16* dst;
  int sld, dld, k0, n0;
  if (t < 4096) {
    const int m = t >> 10, tile = t & 1023;
    k0 = (tile >> 5) * 32; n0 = (tile & 31) * 32;
    src = (m == 0) ? a.wq : (m == 1) ? a.wk : (m == 2) ? a.wv : a.wp;
    sld = 1024; dld = 1024;
    dst = (m < 3) ? (a.dqkv + (size_t)m * 1024 * 1024) : a.dp;
  } else if (t < 8192) {
    const int tile = t - 4096;
    k0 = (tile & 31) * 32; n0 = (tile >> 5) * 32;
    src = a.w1; sld = 4096; dst = a.d1; dld = 1024;
  } else {
    const int tile = t - 8192;
    k0 = (tile >> 5) * 32; n0 = (tile & 31) * 32;
    src = a.w2; sld = 1024; dst = a.d2; dld = 4096;
  }
  transpose_tile(src, sld, dst, dld, k0, n0);
}

// ---------------- fused: ln1 (rows 0..4095) + all weight transposes ----------------
template<bool ADDP>
__global__ __launch_bounds__(256) void ln_tr_fused(
    float* __restrict__ xio, const float* __restrict__ part,
    void* __restrict__ out,
    const float* __restrict__ g, const float* __restrict__ b, TrAll a) {
  if (blockIdx.x < M_) {
    ln_body<true, ADDP>(blockIdx.x, xio, part, out, g, b);
  } else {
    transpose_dispatch(blockIdx.x - M_, a);
  }
}

// ---------------- bias concat: [L][3072] <- bq|bk|bv ----------------
__global__ __launch_bounds__(256) void concat_bias(
    const float* __restrict__ bq, const float* __restrict__ bk,
    const float* __restrict__ bv, float* __restrict__ out) {
  const int i = blockIdx.x * 256 + threadIdx.x;
  const int l = i / QSTR_, c = i % QSTR_;
  const float* src = (c < 1024) ? bq : ((c < 2048) ? bk : bv);
  out[i] = src[l * 1024 + (c & 1023)];
}

// ---------------- bf16 MFMA GEMM 128xBN (4 waves): 3-deep pipeline + swizzle ----
// MODE 0: store bf16; MODE 1: fp32 C += result; MODE 2: store bf16 gelu(result)
template<int MODE, int BN>
__global__ __launch_bounds__(256) void gemm_mfma(
    const __hip_bfloat16* __restrict__ A,
    const __hip_bfloat16* __restrict__ Bt,
    const float* __restrict__ bias,
    void* __restrict__ Cout, int N, int K) {
  __shared__ short As[3][128 * 32];
  __shared__ short Bs[3][BN * 32];
  int bid = blockIdx.y * gridDim.x + blockIdx.x;
  const int nwg = gridDim.x * gridDim.y;
  bid = (bid & 7) * (nwg >> 3) + (bid >> 3);
  const int gn = (bid % gridDim.x) * BN;
  const int gm = (bid / gridDim.x) * 128;

  const int tid = threadIdx.x;
  const int wid = tid >> 6, lane = tid & 63;
  constexpr int MR = (BN == 128) ? 4 : 2;
  const int wm = (BN == 128) ? (wid >> 1) : wid;
  const int wn = (BN == 128) ? (wid & 1) : 0;
  const int fr = lane & 15, kg = lane >> 4;

  const int ldr = lane >> 2;
  const int ldk = (((lane & 3) ^ ((lane >> 3) & 3)) * 8);  // pre-swizzled source chunk
  const unsigned short* ap =
      (const unsigned short*)A + (size_t)(gm + wid * 32 + ldr) * K + ldk;
  const unsigned short* bp =
      (const unsigned short*)Bt +
      (size_t)(gn + ((BN == 128) ? wid * 32 : wid * 16) + ldr) * K + ldk;

  const int nkt = K >> 5;

#define STAGE_T(t, buf)                                                    \
  {                                                                        \
    const unsigned short* a_ = ap + (size_t)(t) * 32;                      \
    g2l16((char*)As[buf] + (wid * 2) * 1024, a_);                          \
    g2l16((char*)As[buf] + (wid * 2 + 1) * 1024, a_ + (size_t)16 * K);     \
    const unsigned short* b_ = bp + (size_t)(t) * 32;                      \
    if (BN == 128) {                                                       \
      g2l16((char*)Bs[buf] + (wid * 2) * 1024, b_);                        \
      g2l16((char*)Bs[buf] + (wid * 2 + 1) * 1024, b_ + (size_t)16 * K);   \
    } else {                                                               \
      g2l16((char*)Bs[buf] + wid * 1024, b_);                              \
    }                                                                      \
  }

  STAGE_T(0, 0);
  STAGE_T(1, 1);

  const int cxa = (kg ^ ((fr >> 1) & 3)) * 8;  // swizzled read chunk (shorts)
  f32x4 acc[MR][4] = {};
  for (int t = 0; t < nkt; ++t) {
    const int buf = t % 3;
    if (t + 2 < nkt) STAGE_T(t + 2, (t + 2) % 3);
    const int rem = nkt - 1 - t;
    if (rem >= 2) {
      if (BN == 128) asm volatile("s_waitcnt vmcnt(8)" ::: "memory");
      else           asm volatile("s_waitcnt vmcnt(6)" ::: "memory");
    } else if (rem == 1) {
      if (BN == 128) asm volatile("s_waitcnt vmcnt(4)" ::: "memory");
      else           asm volatile("s_waitcnt vmcnt(3)" ::: "memory");
    } else {
      asm volatile("s_waitcnt vmcnt(0)" ::: "memory");
    }
    __builtin_amdgcn_s_barrier();
    __builtin_amdgcn_sched_barrier(0);
    s16x8 af[MR], bfr[4];
#pragma unroll
    for (int m = 0; m < MR; ++m)
      af[m] = *reinterpret_cast<const s16x8*>(
          &As[buf][(wm * (16 * MR) + m * 16 + fr) * 32 + cxa]);
#pragma unroll
    for (int n = 0; n < 4; ++n)
      bfr[n] = *reinterpret_cast<const s16x8*>(
          &Bs[buf][(wn * 64 + n * 16 + fr) * 32 + cxa]);
#pragma unroll
    for (int m = 0; m < MR; ++m)
#pragma unroll
      for (int n = 0; n < 4; ++n)
        acc[m][n] = __builtin_amdgcn_mfma_f32_16x16x32_bf16(af[m], bfr[n], acc[m][n], 0, 0, 0);
    __builtin_amdgcn_sched_barrier(0);
    __builtin_amdgcn_s_barrier();
  }
#undef STAGE_T

  const int r0 = gm + wm * (16 * MR);
  const int c0 = gn + wn * 64;
  float bb[4];
#pragma unroll
  for (int n = 0; n < 4; ++n)
    bb[n] = bias ? bias[c0 + n * 16 + fr] : 0.0f;
#pragma unroll
  for (int m = 0; m < MR; ++m) {
#pragma unroll
    for (int j = 0; j < 4; ++j) {
      const int row = r0 + m * 16 + kg * 4 + j;
#pragma unroll
      for (int n = 0; n < 4; ++n) {
        float val = acc[m][n][j] + bb[n];
        const size_t idx = (size_t)row * N + c0 + n * 16 + fr;
        if (MODE == 0) {
          ((unsigned short*)Cout)[idx] = f2b(val);
        } else if (MODE == 1) {
          float* cp = (float*)Cout + idx;
          *cp = *cp + val;
        } else {
          ((unsigned short*)Cout)[idx] = f2b(gelu_f(val));
        }
      }
    }
  }
}

// ------- 128x256 wide GEMM (8 waves, 512 thr): halves B-side cache traffic -------
// MODE: 0 store bf16; 1 fp32 +=; 2 gelu bf16; 3 split-K (z0: X+=acc+bias, z1: P=acc)
template<int MODE>
__global__ __launch_bounds__(512) void gemm_w256(
    const __hip_bfloat16* __restrict__ A,
    const __hip_bfloat16* __restrict__ Bt,
    const float* __restrict__ bias,
    void* __restrict__ Cout, float* __restrict__ P,
    int N, int K, int KS) {
  __shared__ short As[3][128 * 32];
  __shared__ short Bs[3][256 * 32];
  int bid = blockIdx.y * gridDim.x + blockIdx.x;
  const int nwg = gridDim.x * gridDim.y;
  bid = (bid & 7) * (nwg >> 3) + (bid >> 3);
  const int gn = (bid % gridDim.x) * 256;
  const int gm = (bid / gridDim.x) * 128;
  const int koff = (MODE == 3) ? blockIdx.z * KS : 0;

  const int tid = threadIdx.x;
  const int wid = tid >> 6, lane = tid & 63;
  const int wm = wid & 1, wn = wid >> 1;  // 2 x 4 waves of 64x64
  const int fr = lane & 15, kg = lane >> 4;

  const int ldr = lane >> 2;
  const int ldk = (((lane & 3) ^ ((lane >> 3) & 3)) * 8);
  const unsigned short* ap =
      (const unsigned short*)A + (size_t)(gm + wid * 16 + ldr) * K + koff + ldk;
  const unsigned short* bp =
      (const unsigned short*)Bt + (size_t)(gn + wid * 32 + ldr) * K + koff + ldk;

  const int nkt = ((MODE == 3) ? KS : K) >> 5;

#define STAGE_W(t, buf)                                                    \
  {                                                                        \
    g2l16((char*)As[buf] + wid * 1024, ap + (size_t)(t) * 32);             \
    const unsigned short* b_ = bp + (size_t)(t) * 32;                      \
    g2l16((char*)Bs[buf] + (wid * 2) * 1024, b_);                          \
    g2l16((char*)Bs[buf] + (wid * 2 + 1) * 1024, b_ + (size_t)16 * K);     \
  }

  STAGE_W(0, 0);
  STAGE_W(1, 1);

  const int cxa = (kg ^ ((fr >> 1) & 3)) * 8;
  f32x4 acc[4][4] = {};
  for (int t = 0; t < nkt; ++t) {
    const int buf = t % 3;
    if (t + 2 < nkt) STAGE_W(t + 2, (t + 2) % 3);
    const int rem = nkt - 1 - t;
    if (rem >= 2)      asm volatile("s_waitcnt vmcnt(6)" ::: "memory");
    else if (rem == 1) asm volatile("s_waitcnt vmcnt(3)" ::: "memory");
    else               asm volatile("s_waitcnt vmcnt(0)" ::: "memory");
    __builtin_amdgcn_s_barrier();
    __builtin_amdgcn_sched_barrier(0);
    s16x8 af[4], bfr[4];
#pragma unroll
    for (int m = 0; m < 4; ++m)
      af[m] = *reinterpret_cast<const s16x8*>(
          &As[buf][(wm * 64 + m * 16 + fr) * 32 + cxa]);
#pragma unroll
    for (int n = 0; n < 4; ++n)
      bfr[n] = *reinterpret_cast<const s16x8*>(
          &Bs[buf][(wn * 64 + n * 16 + fr) * 32 + cxa]);
#pragma unroll
    for (int m = 0; m < 4; ++m)
#pragma unroll
      for (int n = 0; n < 4; ++n)
        acc[m][n] = __builtin_amdgcn_mfma_f32_16x16x32_bf16(af[m], bfr[n], acc[m][n], 0, 0, 0);
    __builtin_amdgcn_sched_barrier(0);
    __builtin_amdgcn_s_barrier();
  }
#undef STAGE_W

  const int r0 = gm + wm * 64;
  const int c0 = gn + wn * 64;
  if (MODE == 3 && blockIdx.z == 1) {
#pragma unroll
    for (int m = 0; m < 4; ++m)
#pragma unroll
      for (int j = 0; j < 4; ++j) {
        const int row = r0 + m * 16 + kg * 4 + j;
#pragma unroll
        for (int n = 0; n < 4; ++n)
          P[(size_t)row * N + c0 + n * 16 + fr] = acc[m][n][j];
      }
    return;
  }
  float bb[4];
#pragma unroll
  for (int n = 0; n < 4; ++n)
    bb[n] = bias ? bias[c0 + n * 16 + fr] : 0.0f;
#pragma unroll
  for (int m = 0; m < 4; ++m) {
#pragma unroll
    for (int j = 0; j < 4; ++j) {
      const int row = r0 + m * 16 + kg * 4 + j;
#pragma unroll
      for (int n = 0; n < 4; ++n) {
        float val = acc[m][n][j] + bb[n];
        const size_t idx = (size_t)row * N + c0 + n * 16 + fr;
        if (MODE == 0) {
          ((unsigned short*)Cout)[idx] = f2b(val);
        } else if (MODE == 1 || MODE == 3) {
          float* cp = (float*)Cout + idx;
          *cp = *cp + val;
        } else {
          ((unsigned short*)Cout)[idx] = f2b(gelu_f(val));
        }
      }
    }
  }
}

// ------- 256x256 phase-scheduled GEMM (8 waves, BK=64, 128KB dynamic LDS) -------
__global__ __launch_bounds__(512) void gemm_8ph(
    const __hip_bfloat16* __restrict__ A,
    const __hip_bfloat16* __restrict__ Bt,
    const float* __restrict__ bias,
    unsigned short* __restrict__ Cout, int N, int K) {
  extern __shared__ short sm8[];  // 2 halves x (A 256x64 + B 256x64) = 128KB
  int bid = blockIdx.y * gridDim.x + blockIdx.x;
  const int nwg = gridDim.x * gridDim.y;
  bid = (bid & 7) * (nwg >> 3) + (bid >> 3);
  const int gn = (bid % gridDim.x) * 256;
  const int gm = (bid / gridDim.x) * 256;
  const int tid = threadIdx.x;
  const int wid = tid >> 6, lane = tid & 63;
  const int wm = wid >> 2, wn = wid & 3;   // 2m x 4n
  const int fr = lane & 15, kg = lane >> 4;
  const int r8 = lane >> 3, cp = lane & 7;
  const unsigned short* Ap = (const unsigned short*)A;
  const unsigned short* Bp = (const unsigned short*)Bt;
  const int nkt = K >> 6;

#define STAGE8(t, hbase, u)                                                  \
  {                                                                          \
    const int row_ = (u) * 64 + wid * 8 + r8;                                \
    const int c16_ = cp ^ (row_ & 7);                                        \
    g2l16((hbase) + ((u) * 64 + wid * 8) * 128,                              \
          Ap + (size_t)(gm + row_) * K + (size_t)(t) * 64 + c16_ * 8);       \
    g2l16((hbase) + 32768 + ((u) * 64 + wid * 8) * 128,                      \
          Bp + (size_t)(gn + row_) * K + (size_t)(t) * 64 + c16_ * 8);       \
  }

#pragma unroll
  for (int u = 0; u < 4; ++u) STAGE8(0, (char*)sm8, u);
  asm volatile("s_waitcnt vmcnt(0)" ::: "memory");
  __builtin_amdgcn_s_barrier();

  f32x4 acc[8][4] = {};
  for (int t = 0; t < nkt; ++t) {
    char* cur = (char*)sm8 + (t & 1) * 65536;
    char* nxt = (char*)sm8 + ((t & 1) ^ 1) * 65536;
    __builtin_amdgcn_sched_barrier(0);
#pragma unroll
    for (int p = 0; p < 4; ++p) {
      if (t + 1 < nkt) STAGE8(t + 1, nxt, p);
      s16x8 af[2][2], bfr[4][2];
#pragma unroll
      for (int mm = 0; mm < 2; ++mm) {
        const int row = wm * 128 + (p * 2 + mm) * 16 + fr;
#pragma unroll
        for (int kk = 0; kk < 2; ++kk)
          af[mm][kk] = *reinterpret_cast<const s16x8*>(
              cur + row * 128 + (((kk * 4 + kg) ^ (row & 7)) << 4));
      }
#pragma unroll
      for (int n = 0; n < 4; ++n) {
        const int row = wn * 64 + n * 16 + fr;
#pragma unroll
        for (int kk = 0; kk < 2; ++kk)
          bfr[n][kk] = *reinterpret_cast<const s16x8*>(
              cur + 32768 + row * 128 + (((kk * 4 + kg) ^ (row & 7)) << 4));
      }
      __builtin_amdgcn_s_setprio(1);
#pragma unroll
      for (int kk = 0; kk < 2; ++kk)
#pragma unroll
        for (int mm = 0; mm < 2; ++mm)
#pragma unroll
          for (int n = 0; n < 4; ++n)
            acc[p * 2 + mm][n] = __builtin_amdgcn_mfma_f32_16x16x32_bf16(
                af[mm][kk], bfr[n][kk], acc[p * 2 + mm][n], 0, 0, 0);
      __builtin_amdgcn_s_setprio(0);
    }
    if (t + 1 < nkt) {
      asm volatile("s_waitcnt vmcnt(0)" ::: "memory");
      __builtin_amdgcn_s_barrier();
    }
  }
#undef STAGE8

  const int r0 = gm + wm * 128;
  const int c0 = gn + wn * 64;
  float bb[4];
#pragma unroll
  for (int n = 0; n < 4; ++n) bb[n] = bias[c0 + n * 16 + fr];
#pragma unroll
  for (int m = 0; m < 8; ++m)
#pragma unroll
    for (int j = 0; j < 4; ++j) {
      const int row = r0 + m * 16 + kg * 4 + j;
#pragma unroll
      for (int n = 0; n < 4; ++n)
        Cout[(size_t)row * N + c0 + n * 16 + fr] =
            f2b(gelu_f(acc[m][n][j] + bb[n]));
    }
}

// ---------------- MFMA flash attention v9: single barrier + T13 defer-max ----
// v8 structure (Ks[3] ring, Vt[2], one barrier/visit) + defer-max: when the
// wave-uniform test (mloc - m_run)*C <= 8 passes, keep the old max and skip
// the rescale pass entirely (P bounded by 2^8, safe in fp32 psum / bf16 P).
__global__ __launch_bounds__(512) void attn_mfma(
    const __hip_bfloat16* __restrict__ qkv, __hip_bfloat16* __restrict__ yg) {
  const int x = blockIdx.x;
  const int qb = (x < 2) ? (3 - x) : (x - 2);  // balanced pairing (3,0),(2,1)
  const int hh = blockIdx.y;
  const int bb = blockIdx.z;
  __shared__ short Qs[256 * 64];    // Q staging, then P (32KB)
  __shared__ short Ks[3][64 * 64];  // 24KB prefetch ring
  __shared__ short Vt[2][64 * 64];  // 16KB double buffer
  const int tid = threadIdx.x;
  const int wid = tid >> 6, lane = tid & 63;
  const int fr = lane & 15, kg = lane >> 4;
  const size_t qb_base = (size_t)bb * T_ * QSTR_ + (size_t)hh * DH_;
  const unsigned short* qgp = (const unsigned short*)qkv + qb_base;
  const unsigned short* kgp = qgp + 1024;
  const unsigned short* vgp = qgp + 2048;
  const float C = 0.125f * 1.4426950408889634f;  // scale * log2(e)

  const int r8 = lane >> 3, cp = lane & 7;
#pragma unroll
  for (int u = 0; u < 4; ++u) {
    const int row = wid * 32 + u * 8 + r8;
    const int c16 = cp ^ (row & 7);
    g2l16((char*)Qs + (wid * 32 + u * 8) * 128,
          qgp + (size_t)(qb * 256 + row) * QSTR_ + c16 * 8);
  }
  {
    const int row = wid * 8 + r8;
    const int c16 = cp ^ (row & 7);
    g2l16((char*)Ks[0] + (wid * 8) * 128, kgp + (size_t)row * QSTR_ + c16 * 8);
  }
  const int kv0 = tid >> 3;
  const int d0 = (tid & 7) * 8;
  const int rot = tid & 7;
  s16x8 sva = *reinterpret_cast<const s16x8*>(vgp + (size_t)kv0 * QSTR_ + d0);

  asm volatile("s_waitcnt vmcnt(0)" ::: "memory");
  __syncthreads();
  s16x8 qf[2][2];
#pragma unroll
  for (int rg = 0; rg < 2; ++rg) {
    const int row = wid * 32 + rg * 16 + fr;
    const char* rp = (const char*)Qs + row * 128;
    qf[rg][0] = *reinterpret_cast<const s16x8*>(rp + (((0 + kg) ^ (row & 7)) << 4));
    qf[rg][1] = *reinterpret_cast<const s16x8*>(rp + (((4 + kg) ^ (row & 7)) << 4));
  }

  f32x4 acco[2][4] = {};
  float m_run[2] = {-INFINITY, -INFINITY};
  float l_run[2] = {0.f, 0.f};

  const int q16hi = qb * 16 + wid * 2 + 1;
  const int ntile = 4 * qb + 4;
  for (int kt = 0; kt < ntile; ++kt) {
    const int kb3 = kt % 3;
    const int vb = kt & 1;
    asm volatile("s_waitcnt vmcnt(0)" ::: "memory");  // own K(kt)/V(kt) loads done
    // ---- scatter V(kt) regs -> Vt[vb] (swizzled transpose) ----
#pragma unroll
    for (int j = 0; j < 8; ++j) {
      const int jj = (j + rot) & 7;
      const int d = d0 + jj;
      *(short*)((char*)Vt[vb] + d * 128 + ((((kv0 >> 3) ^ jj) & 7) << 4) + (kv0 & 7) * 2) = sva[jj];
    }
    // ---- prefetch tile kt+1 (K into ring slot (kt+1)%3; V into regs) ----
    if (kt + 1 < ntile) {
      const int row = wid * 8 + r8;
      const int c16 = cp ^ (row & 7);
      g2l16((char*)Ks[(kt + 1) % 3] + (wid * 8) * 128,
            kgp + (size_t)((kt + 1) * 64 + row) * QSTR_ + c16 * 8);
      sva = *reinterpret_cast<const s16x8*>(
          vgp + (size_t)((kt + 1) * 64 + kv0) * QSTR_ + d0);
    }
    __syncthreads();  // single barrier: V(kt) scatter + all waves' K(kt) visible
    __builtin_amdgcn_sched_barrier(0);

    if (kt * 4 <= q16hi) {
      f32x4 accs[2][4] = {};
      __builtin_amdgcn_s_setprio(1);
#pragma unroll
      for (int n = 0; n < 4; ++n) {
        const int row = n * 16 + fr;
        const char* rp = (const char*)Ks[kb3] + row * 128;
        s16x8 kf0 = *reinterpret_cast<const s16x8*>(rp + (((0 + kg) ^ (row & 7)) << 4));
        s16x8 kf1 = *reinterpret_cast<const s16x8*>(rp + (((4 + kg) ^ (row & 7)) << 4));
#pragma unroll
        for (int rg = 0; rg < 2; ++rg) {
          accs[rg][n] = __builtin_amdgcn_mfma_f32_16x16x32_bf16(kf0, qf[rg][0], accs[rg][n], 0, 0, 0);
          accs[rg][n] = __builtin_amdgcn_mfma_f32_16x16x32_bf16(kf1, qf[rg][1], accs[rg][n], 0, 0, 0);
        }
      }
      __builtin_amdgcn_s_setprio(0);
#pragma unroll
      for (int rg = 0; rg < 2; ++rg) {
        const int q16 = qb * 16 + wid * 2 + rg;
        float mloc = -3.0e38f;
#pragma unroll
        for (int n = 0; n < 4; ++n)
          if (kt * 4 + n <= q16)
#pragma unroll
            for (int j = 0; j < 4; ++j) mloc = fmaxf(mloc, accs[rg][n][j]);
        mloc = fmaxf(mloc, __shfl_xor(mloc, 16));
        mloc = fmaxf(mloc, __shfl_xor(mloc, 32));
        // T13 defer-max: skip rescale when max growth bounded (wave-uniform)
        if (!__all((mloc - m_run[rg]) * C <= 8.0f)) {
          const float mn = fmaxf(m_run[rg], mloc);
          const float a_ = EXP2F((m_run[rg] - mn) * C);
          m_run[rg] = mn;
          l_run[rg] *= a_;
          float aj[4];
#pragma unroll
          for (int j = 0; j < 4; ++j) aj[j] = __shfl(a_, kg * 4 + j);
#pragma unroll
          for (int dt = 0; dt < 4; ++dt)
#pragma unroll
            for (int j = 0; j < 4; ++j) acco[rg][dt][j] *= aj[j];
        }
        const float mn = m_run[rg];
        const int prow = wid * 32 + rg * 16 + fr;
        char* pbase = (char*)Qs + prow * 128 + (kg & 1) * 8;
        const int rxor = prow & 7;
        float psum = 0.f;
#pragma unroll
        for (int n = 0; n < 4; ++n) {
          const bool dead = (kt * 4 + n > q16);
          unsigned long long pk = 0;
#pragma unroll
          for (int j = 0; j < 4; ++j) {
            const float p = dead ? 0.0f : EXP2F((accs[rg][n][j] - mn) * C);
            psum += p;
            pk |= (unsigned long long)f2b(p) << (16 * j);
          }
          *reinterpret_cast<unsigned long long*>(
              pbase + (((n * 2 + (kg >> 1)) ^ rxor) << 4)) = pk;
        }
        l_run[rg] += psum;
      }
      __builtin_amdgcn_s_setprio(1);
#pragma unroll
      for (int rg = 0; rg < 2; ++rg) {
        const int prow = wid * 32 + rg * 16 + fr;
        const char* pp = (const char*)Qs + prow * 128;
#pragma unroll
        for (int kk = 0; kk < 2; ++kk) {
          const s16x8 pf = *reinterpret_cast<const s16x8*>(
              pp + ((((kk * 4 + kg) ^ (prow & 7)) & 7) << 4));
#pragma unroll
          for (int dt = 0; dt < 4; ++dt) {
            const int vrow = dt * 16 + fr;
            const s16x8 vf = *reinterpret_cast<const s16x8*>(
                (const char*)Vt[vb] + vrow * 128 + ((((kk * 4 + kg) ^ (vrow & 7)) & 7) << 4));
            acco[rg][dt] = __builtin_amdgcn_mfma_f32_16x16x32_bf16(pf, vf, acco[rg][dt], 0, 0, 0);
          }
        }
      }
      __builtin_amdgcn_s_setprio(0);
    }
  }

  unsigned short* yp = (unsigned short*)yg + (size_t)bb * T_ * D_ + (size_t)hh * DH_;
#pragma unroll
  for (int rg = 0; rg < 2; ++rg) {
    float lt = l_run[rg];
    lt += __shfl_xor(lt, 16);
    lt += __shfl_xor(lt, 32);
    const float linv = 1.0f / lt;
    float lj[4];
#pragma unroll
    for (int j = 0; j < 4; ++j) lj[j] = __shfl(linv, kg * 4 + j);
#pragma unroll
    for (int dt = 0; dt < 4; ++dt)
#pragma unroll
      for (int j = 0; j < 4; ++j) {
        const int row = qb * 256 + wid * 32 + rg * 16 + kg * 4 + j;
        yp[(size_t)row * D_ + dt * 16 + fr] = f2b(acco[rg][dt][j] * lj[j]);
      }
  }
}

extern "C" void kernel_launch(void* const* d_in, const int* in_sizes, int n_in,
                              void* d_out, int out_size, void* d_ws, size_t ws_size,
                              hipStream_t stream) {
  (void)in_sizes; (void)n_in; (void)out_size; (void)ws_size;
  const float* seq  = (const float*)d_in[0];
  const float* Wq   = (const float*)d_in[1];
  const float* bq   = (const float*)d_in[2];
  const float* Wk   = (const float*)d_in[3];
  const float* bk   = (const float*)d_in[4];
  const float* Wv   = (const float*)d_in[5];
  const float* bv   = (const float*)d_in[6];
  const float* Wp   = (const float*)d_in[7];
  const float* bp   = (const float*)d_in[8];
  const float* ln1g = (const float*)d_in[9];
  const float* ln1b = (const float*)d_in[10];
  const float* ln2g = (const float*)d_in[11];
  const float* ln2b = (const float*)d_in[12];
  const float* W1   = (const float*)d_in[13];
  const float* b1   = (const float*)d_in[14];
  const float* W2   = (const float*)d_in[15];
  const float* b2   = (const float*)d_in[16];
  const float* lnfg = (const float*)d_in[17];
  const float* lnfb = (const float*)d_in[18];

  float* x = (float*)d_out;
  char* ws = (char*)d_ws;
  const size_t MB = 1024ull * 1024ull;
  typedef __hip_bfloat16 bf16;
  bf16*  wtqkv = (bf16*)(ws + 0 * MB);    // [3072][1024]
  bf16*  wtp   = (bf16*)(ws + 6 * MB);    // [1024][1024]
  bf16*  wtF1  = (bf16*)(ws + 8 * MB);    // [4096][1024]
  bf16*  wtF2  = (bf16*)(ws + 16 * MB);   // [1024][4096]
  bf16*  hb    = (bf16*)(ws + 24 * MB);   // [4096][1024]
  bf16*  qkv   = (bf16*)(ws + 32 * MB);   // [4096][3072]
  bf16*  mid   = (bf16*)(ws + 56 * MB);   // [4096][4096]
  float* bqkv  = (float*)(ws + 88 * MB);  // [8][3072]
  float* part  = (float*)(ws + 32 * MB);  // W2 split-K partial (qkv region dead
                                          // during FFN; consumed by next ln1)

  hipMemcpyAsync(x, seq, (size_t)M_ * D_ * sizeof(float), hipMemcpyDeviceToDevice, stream);

  const dim3 blk(256);
  const dim3 blkw(512);
  concat_bias<<<96, blk, 0, stream>>>(bq, bk, bv, bqkv);

  for (int i = 0; i < 8; ++i) {
    const size_t wo  = (size_t)i * D_ * D_;
    const size_t vo  = (size_t)i * D_;
    const size_t w1o = (size_t)i * D_ * 4 * D_;

    TrAll ta;
    ta.wq = Wq + wo; ta.wk = Wk + wo; ta.wv = Wv + wo; ta.wp = Wp + wo;
    ta.w1 = W1 + w1o; ta.w2 = W2 + w1o;
    ta.dqkv = wtqkv; ta.dp = wtp; ta.d1 = wtF1; ta.d2 = wtF2;
    // fused ln1 + all weight transposes: 4096 LN rows + 12288 transpose tiles
    if (i == 0)
      ln_tr_fused<false><<<16384, blk, 0, stream>>>(x, nullptr, hb, ln1g + vo, ln1b + vo, ta);
    else
      ln_tr_fused<true><<<16384, blk, 0, stream>>>(x, part, hb, ln1g + vo, ln1b + vo, ta);
    // fused QKV: 128x256 tiles, grid (12,32) = 384 blocks
    gemm_w256<0><<<dim3(12, 32), blkw, 0, stream>>>(
        hb, wtqkv, bqkv + (size_t)i * QSTR_, qkv, nullptr, QSTR_, 1024, 0);
    // attention: QBLK=256, 512 threads, grid (4,16,4)
    attn_mfma<<<dim3(4, 16, 4), blkw, 0, stream>>>(qkv, hb);
    // proj: 128x64 tiles, grid (16,32) = 512 blocks
    gemm_mfma<1, 64><<<dim3(16, 32), blk, 0, stream>>>(hb, wtp, bp + vo, x, 1024, 1024);
    ln_kernel<true, false><<<M_, blk, 0, stream>>>(x, nullptr, hb, ln2g + vo, ln2b + vo);
    // FFN up: 256x256 phase-scheduled, grid (16,16) = 256 blocks, 128KB dyn LDS
    gemm_8ph<<<dim3(16, 16), blkw, 131072, stream>>>(
        hb, wtF1, b1 + (size_t)i * 4096, (unsigned short*)mid, 4096, 1024);
    // FFN down: 128x256 split-K=2, grid (4,32,2) = 256 blocks
    gemm_w256<3><<<dim3(4, 32, 2), blkw, 0, stream>>>(
        mid, wtF2, b2 + vo, x, part, 1024, 4096, 2048);
  }
  ln_kernel<false, true><<<M_, blk, 0, stream>>>(x, part, x, lnfg, lnfb);
}